// Round 12
// baseline (88.256 us; speedup 1.0000x reference)
//
#include <hip/hip_runtime.h>
#include <hip/hip_bf16.h>

#define D_ 256
#define H_ 8
#define B_ 2
#define S_ 2048
#define MTOT 4096
#define AUGQ 64          // q(32) + pq(16) + [maskbias](1) + pad(15)
#define NBH 16           // B_*H_
#define NSPLIT 4
#define NJ 8             // key tiles (of 64) per split
#define LOG2E 1.4426950408889634f

typedef __attribute__((ext_vector_type(8))) short short8;
typedef __attribute__((ext_vector_type(4))) short short4v;
typedef __attribute__((ext_vector_type(4))) float f32x4;

static __device__ __forceinline__ short bf16_of(float f) {
  union { __hip_bfloat16 h; short s; } u;
  u.h = __float2bfloat16(f);
  return u.s;
}
static __device__ __forceinline__ float f_of_bf16(short s) {
  union { float f; unsigned int u; } u;
  u.u = ((unsigned int)(unsigned short)s) << 16;
  return u.f;
}
static __device__ __forceinline__ float fast_exp2(float x) {
#if defined(__has_builtin) && __has_builtin(__builtin_amdgcn_exp2f)
  return __builtin_amdgcn_exp2f(x);
#else
  return exp2f(x);
#endif
}

// key permutation within a 64-key tile: V column c holds key sinv(c)
static __device__ __forceinline__ int sinv64(int c) {
  return (((((c >> 2) & 1) << 1) | ((c >> 5) & 1)) << 4) + (((c >> 3) & 3) << 2) + (c & 3);
}

// ---------------- prep: sectioned by blockIdx ----------------
// blocks 0..47   : Wqkv transpose tiles (64x64 via LDS)
// blocks 48..63  : Wo transpose tiles
// blocks 64..575 : X f32 -> bf16 (Xb)
// blocks 576..703: pq/pk augmented cols (full 64-col writes: pads must be 0)
// blocks 704..959: pq into VaT (sigma-permuted)

__global__ __launch_bounds__(256) void prep_all(
    const float* __restrict__ Wq, const float* __restrict__ Wk,
    const float* __restrict__ Wv, const float* __restrict__ Wo,
    const float* __restrict__ X, const float* __restrict__ coords,
    const int* __restrict__ mask,
    const float* __restrict__ Wpq, const float* __restrict__ bpq,
    const float* __restrict__ Wpk, const float* __restrict__ bpk,
    short* __restrict__ Wqkv_t, short* __restrict__ Wo_t,
    short* __restrict__ Xb,
    short* __restrict__ Qa, short* __restrict__ Ka, short* __restrict__ VaT) {
  int bid = blockIdx.x, tid = threadIdx.x;

  if (bid < 64) {
    __shared__ short T[64][72];
    const float* src;
    short* dst;
    int k0, n0g;
    if (bid < 48) {
      int nt = bid >> 2;
      k0 = (bid & 3) * 64;
      n0g = nt * 64;
      src = (n0g < 256) ? Wq : (n0g < 512 ? Wk : Wv);
      dst = Wqkv_t;
    } else {
      int t2 = bid - 48;
      k0 = (t2 & 3) * 64;
      n0g = (t2 >> 2) * 64;
      src = Wo;
      dst = Wo_t;
    }
    int ncol = n0g & 255;
    int rr = tid >> 4, cc = (tid & 15) * 4;
#pragma unroll
    for (int i = 0; i < 4; i++) {
      int r = rr + i * 16;
      f32x4 v = *reinterpret_cast<const f32x4*>(&src[(size_t)(k0 + r) * 256 + ncol + cc]);
      T[cc + 0][r] = bf16_of(v[0]);
      T[cc + 1][r] = bf16_of(v[1]);
      T[cc + 2][r] = bf16_of(v[2]);
      T[cc + 3][r] = bf16_of(v[3]);
    }
    __syncthreads();
    int n = tid >> 2, kk = (tid & 3) * 16;
    *reinterpret_cast<short8*>(&dst[(size_t)(n0g + n) * 256 + k0 + kk]) =
        *reinterpret_cast<const short8*>(&T[n][kk]);
    *reinterpret_cast<short8*>(&dst[(size_t)(n0g + n) * 256 + k0 + kk + 8]) =
        *reinterpret_cast<const short8*>(&T[n][kk + 8]);
    return;
  }

  if (bid < 576) {
    size_t i = (size_t)(bid - 64) * 2048 + tid * 8;
    f32x4 v0 = *reinterpret_cast<const f32x4*>(&X[i]);
    f32x4 v1 = *reinterpret_cast<const f32x4*>(&X[i + 4]);
    short8 o;
    o[0] = bf16_of(v0[0]); o[1] = bf16_of(v0[1]); o[2] = bf16_of(v0[2]); o[3] = bf16_of(v0[3]);
    o[4] = bf16_of(v1[0]); o[5] = bf16_of(v1[1]); o[6] = bf16_of(v1[2]); o[7] = bf16_of(v1[3]);
    *reinterpret_cast<short8*>(&Xb[i]) = o;
    return;
  }

  if (bid < 704) {
    // pq/pk cols 32..47 (Q pre-scaled by log2e) + bias col 48 + zero pads 49..63
    int idx = (bid - 576) * 256 + tid;
    int m = idx >> 3, h = idx & 7;
    int b = m >> 11, s = m & 2047;
    float r0 = coords[m * 9 + 3], r1 = coords[m * 9 + 4], r2 = coords[m * 9 + 5];
    size_t base = ((size_t)(b * 8 + h) * S_ + s) * AUGQ;
    short8 pqv[2], pkv[2];
#pragma unroll
    for (int c = 0; c < 2; c++)
#pragma unroll
      for (int i = 0; i < 8; i++) {
        int j = h * 16 + c * 8 + i;
        float pq = r0 * Wpq[j] + r1 * Wpq[128 + j] + r2 * Wpq[256 + j] + bpq[j];
        float pk = r0 * Wpk[j] + r1 * Wpk[128 + j] + r2 * Wpk[256 + j] + bpk[j];
        pqv[c][i] = bf16_of(pq * LOG2E);
        pkv[c][i] = bf16_of(pk * 0.25f);
      }
    short8 padq = {};
    padq[0] = bf16_of(LOG2E);  // Qa col 48 multiplies Ka's mask-bias col
    short8 padk = {};
    padk[0] = mask[m] ? (short)0 : bf16_of(-1e9f);
    short8 z = {};
    *reinterpret_cast<short8*>(&Qa[base + 32]) = pqv[0];
    *reinterpret_cast<short8*>(&Qa[base + 40]) = pqv[1];
    *reinterpret_cast<short8*>(&Qa[base + 48]) = padq;
    *reinterpret_cast<short8*>(&Qa[base + 56]) = z;
    *reinterpret_cast<short8*>(&Ka[base + 32]) = pkv[0];
    *reinterpret_cast<short8*>(&Ka[base + 40]) = pkv[1];
    *reinterpret_cast<short8*>(&Ka[base + 48]) = padk;
    *reinterpret_cast<short8*>(&Ka[base + 56]) = z;
    return;
  }

  {
    // pq (unscaled) into VaT, sigma-permuted per 64
    int idx = (bid - 704) * 256 + tid;
    int s8 = idx & 255, p = (idx >> 8) & 15, bh = idx >> 12;
    int b = bh >> 3, h = bh & 7, j = h * 16 + p;
    float w0 = Wpq[j], w1 = Wpq[128 + j], w2 = Wpq[256 + j], bb = bpq[j];
    short8 o;
#pragma unroll
    for (int i = 0; i < 8; i++) {
      int c = (s8 & 7) * 8 + i;
      int m = b * 2048 + (s8 >> 3) * 64 + sinv64(c);
      o[i] = bf16_of(coords[m * 9 + 3] * w0 + coords[m * 9 + 4] * w1 +
                     coords[m * 9 + 5] * w2 + bb);
    }
    *reinterpret_cast<short8*>(&VaT[((size_t)bh * 48 + 32 + p) * S_ + s8 * 8]) = o;
  }
}

// ---------------- QKV GEMM (M=4096, N=768, K=256), bf16 in, vector epilogue ----------------

__global__ __launch_bounds__(256) void qkv_gemm(
    const short* __restrict__ Xb, const short* __restrict__ Wt,
    const float* __restrict__ bq, const float* __restrict__ bk, const float* __restrict__ bv,
    short* __restrict__ Qa, short* __restrict__ Ka, short* __restrict__ VaT) {
  __shared__ __align__(16) short As[64 * 136];
  __shared__ __align__(16) short Bs[64 * 136];
  int m0 = blockIdx.x * 64, n0 = blockIdx.y * 64;
  int tid = threadIdx.x, lane = tid & 63, w = tid >> 6;
  int t = lane & 15, g = lane >> 4, kf = g * 8;
  int wr = (w >> 1) * 32, wc = (w & 1) * 32;
  f32x4 acc[2][2] = {};
  int srow = tid >> 2, skc = (tid & 3) * 32;
  for (int ph = 0; ph < 2; ph++) {
    int k0 = ph * 128;
    __syncthreads();
    {
      const uint4* xsrc = reinterpret_cast<const uint4*>(&Xb[(size_t)(m0 + srow) * 256 + k0 + skc]);
      const uint4* wsrc = reinterpret_cast<const uint4*>(&Wt[(size_t)(n0 + srow) * 256 + k0 + skc]);
#pragma unroll
      for (int i = 0; i < 4; i++)
        *reinterpret_cast<uint4*>(&As[srow * 136 + skc + i * 8]) = xsrc[i];
#pragma unroll
      for (int i = 0; i < 4; i++)
        *reinterpret_cast<uint4*>(&Bs[srow * 136 + skc + i * 8]) = wsrc[i];
    }
    __syncthreads();
#pragma unroll
    for (int kk = 0; kk < 4; kk++) {
      short8 a[2], bb[2];
#pragma unroll
      for (int i = 0; i < 2; i++)
        a[i] = *reinterpret_cast<const short8*>(&As[(wr + i * 16 + t) * 136 + kk * 32 + kf]);
#pragma unroll
      for (int jj = 0; jj < 2; jj++)
        bb[jj] = *reinterpret_cast<const short8*>(&Bs[(wc + jj * 16 + t) * 136 + kk * 32 + kf]);
#pragma unroll
      for (int i = 0; i < 2; i++)
#pragma unroll
        for (int jj = 0; jj < 2; jj++)
          acc[i][jj] = __builtin_amdgcn_mfma_f32_16x16x32_bf16(a[i], bb[jj], acc[i][jj], 0, 0, 0);
    }
  }
  __syncthreads();
  short* Cs = As;
  const float scale = 0.17677669529663687f * LOG2E;  // (1/sqrt(32)) * log2e
  int b = m0 >> 11, sbase = m0 & 2047;
#pragma unroll
  for (int i = 0; i < 2; i++)
#pragma unroll
    for (int jj = 0; jj < 2; jj++)
#pragma unroll
      for (int r = 0; r < 4; r++) {
        int rl = wr + i * 16 + g * 4 + r;
        int cl = wc + jj * 16 + t;
        int n = n0 + cl;
        float v = acc[i][jj][r];
        if (n < 256) v = (v + bq[n]) * scale;
        else if (n < 512) v = v + bk[n - 256];
        else v = v + bv[n - 512];
        Cs[rl * 72 + cl] = bf16_of(v);
      }
  __syncthreads();
  if (n0 < 512) {
#pragma unroll
    for (int i2 = 0; i2 < 2; i2++) {
      int task = tid + i2 * 256;
      int row = task >> 3, c = task & 7;
      int n = n0 + c * 8;
      short* dst = (n < 256) ? Qa : Ka;
      int nn = n & 255;
      int hh = nn >> 5, d = nn & 31;
      *reinterpret_cast<short8*>(&dst[((size_t)(b * 8 + hh) * S_ + sbase + row) * AUGQ + d]) =
          *reinterpret_cast<const short8*>(&Cs[row * 72 + c * 8]);
    }
  } else {
    int hv0 = (n0 - 512) >> 5;
#pragma unroll
    for (int i2 = 0; i2 < 2; i2++) {
      int task = tid + i2 * 256;
      int fl = task >> 3, s8 = task & 7;
      short8 o;
#pragma unroll
      for (int i = 0; i < 8; i++) o[i] = Cs[sinv64(s8 * 8 + i) * 72 + fl];
      int hh = hv0 + (fl >> 5), d = fl & 31;
      *reinterpret_cast<short8*>(&VaT[((size_t)(b * 8 + hh) * 48 + d) * S_ + sbase + s8 * 8]) = o;
    }
  }
}

// ---------------- flash attention: NO LDS staging, barrier-free main loop ----------------
// grid 1024 (XCD-swizzled); block 256 = 4 waves, each wave 32 queries.
// K/V fragments read directly from global (L1/L2-resident per XCD).
// V keys sigma-permuted so QK outputs form K=32 PV fragments in-register.

__global__ __launch_bounds__(256, 4) void attn(
    const short* __restrict__ Qa, const short* __restrict__ Ka,
    const short* __restrict__ VaT,
    short* __restrict__ Ctx, float* __restrict__ AccL) {
  __shared__ __align__(16) float Of[128 * 52];   // epilogue transpose (26624 B)

  int bid = blockIdx.x;
  int xcd = bid & 7, slot = bid >> 3;       // slot 0..127
  int gidx = xcd * 8 + (slot >> 4);         // 0..63 = bhv*4+split
  int it = slot & 15;
  int split = gidx & 3;
  int bhv = gidx >> 2;

  int tid = threadIdx.x, lane = tid & 63, w = tid >> 6;
  int t = lane & 15, g = lane >> 4, kf = g * 8;
  int q0w = it * 128 + w * 32;
  size_t bh = (size_t)bhv * S_;

  short8 aq[2][2];
#pragma unroll
  for (int g2 = 0; g2 < 2; g2++)
#pragma unroll
    for (int c = 0; c < 2; c++)
      aq[g2][c] = *reinterpret_cast<const short8*>(
          &Qa[(bh + q0w + g2 * 16 + t) * AUGQ + c * 32 + kf]);

  f32x4 OaccA[3] = {}, OaccB[3] = {};
  float lsum0 = 0.f, lsum1 = 0.f;
  const int jt0 = split * NJ;
  const short* Kbh = &Ka[bh * AUGQ];
  const short* Vbh = &VaT[(size_t)bhv * 48 * S_];

  for (int j = 0; j < NJ; j++) {
    int jt = jt0 + j;
    const short* kt = &Kbh[(size_t)(jt * 64) * AUGQ];
    const short* vt = &Vbh[jt * 64];
    // fragment loads straight from global (L1/L2)
    short8 ka0[4], ka1[4], va[3][2];
#pragma unroll
    for (int sub = 0; sub < 4; sub++) {
      ka0[sub] = *reinterpret_cast<const short8*>(&kt[(sub * 16 + t) * AUGQ + kf]);
      ka1[sub] = *reinterpret_cast<const short8*>(&kt[(sub * 16 + t) * AUGQ + 32 + kf]);
    }
#pragma unroll
    for (int tt = 0; tt < 3; tt++)
#pragma unroll
      for (int w2 = 0; w2 < 2; w2++)
        va[tt][w2] = *reinterpret_cast<const short8*>(
            &vt[(size_t)(tt * 16 + t) * S_ + w2 * 32 + kf]);

    short8 pA[2], pB[2];
#pragma unroll
    for (int sub = 0; sub < 4; sub++) {
      f32x4 sA = {}, sB = {};
      sA = __builtin_amdgcn_mfma_f32_16x16x32_bf16(ka0[sub], aq[0][0], sA, 0, 0, 0);
      sA = __builtin_amdgcn_mfma_f32_16x16x32_bf16(ka1[sub], aq[0][1], sA, 0, 0, 0);
      sB = __builtin_amdgcn_mfma_f32_16x16x32_bf16(ka0[sub], aq[1][0], sB, 0, 0, 0);
      sB = __builtin_amdgcn_mfma_f32_16x16x32_bf16(ka1[sub], aq[1][1], sB, 0, 0, 0);
      float a0 = fast_exp2(sA[0]), a1 = fast_exp2(sA[1]);
      float a2 = fast_exp2(sA[2]), a3 = fast_exp2(sA[3]);
      float b0 = fast_exp2(sB[0]), b1 = fast_exp2(sB[1]);
      float b2 = fast_exp2(sB[2]), b3 = fast_exp2(sB[3]);
      lsum0 += (a0 + a1) + (a2 + a3);
      lsum1 += (b0 + b1) + (b2 + b3);
      int ww = sub & 1, off = (sub >> 1) * 4;
      pA[ww][off + 0] = bf16_of(a0); pA[ww][off + 1] = bf16_of(a1);
      pA[ww][off + 2] = bf16_of(a2); pA[ww][off + 3] = bf16_of(a3);
      pB[ww][off + 0] = bf16_of(b0); pB[ww][off + 1] = bf16_of(b1);
      pB[ww][off + 2] = bf16_of(b2); pB[ww][off + 3] = bf16_of(b3);
    }
    __builtin_amdgcn_s_setprio(1);
#pragma unroll
    for (int tt = 0; tt < 3; tt++) {
#pragma unroll
      for (int w2 = 0; w2 < 2; w2++) {
        OaccA[tt] = __builtin_amdgcn_mfma_f32_16x16x32_bf16(va[tt][w2], pA[w2], OaccA[tt], 0, 0, 0);
        OaccB[tt] = __builtin_amdgcn_mfma_f32_16x16x32_bf16(va[tt][w2], pB[w2], OaccB[tt], 0, 0, 0);
      }
    }
    __builtin_amdgcn_s_setprio(0);
  }

  // epilogue: reduce lsums; transpose O via LDS; bf16 partial ctx out
  lsum0 += __shfl_xor(lsum0, 16); lsum0 += __shfl_xor(lsum0, 32);
  lsum1 += __shfl_xor(lsum1, 16); lsum1 += __shfl_xor(lsum1, 32);

#pragma unroll
  for (int tt = 0; tt < 3; tt++)
#pragma unroll
    for (int r = 0; r < 4; r++) {
      Of[(w * 32 + t) * 52 + tt * 16 + g * 4 + r] = OaccA[tt][r];
      Of[(w * 32 + 16 + t) * 52 + tt * 16 + g * 4 + r] = OaccB[tt][r];
    }
  if (lane < 16) {
    size_t lb = (size_t)(split * NBH + bhv) * S_ + q0w + lane;
    AccL[lb] = lsum0;
    AccL[lb + 16] = lsum1;
  }
  __syncthreads();
  short* CtxP = Ctx + (size_t)split * NBH * S_ * 48;
  size_t obase = bh + it * 128;
  for (int task = tid; task < 768; task += 256) {
    int row = task / 6, c8 = task % 6;
    const float* src = &Of[row * 52 + c8 * 8];
    short8 o;
#pragma unroll
    for (int i = 0; i < 8; i++) o[i] = bf16_of(src[i]);
    *reinterpret_cast<short8*>(&CtxP[(obase + row) * 48 + c8 * 8]) = o;
  }
}

// ---------------- output projection + fused 4-way split-merge + fused point_proj ----------------

__global__ __launch_bounds__(512) void out_gemm(
    const short* __restrict__ Ctx, const float* __restrict__ AccL,
    const short* __restrict__ Wot, const float* __restrict__ bo,
    const float* __restrict__ Wpo, const float* __restrict__ bpo,
    float* __restrict__ Out) {
  const size_t CTXSZ = (size_t)NBH * S_ * 48;
  int m0 = blockIdx.x * 64;
  int tid = threadIdx.x;
  int b = m0 >> 11, sbase = m0 & 2047;

  if (blockIdx.y == 4) {
    int row = tid >> 3, hh = tid & 7;
    int m = m0 + row, s = sbase + row;
    size_t rowO = (size_t)(b * 8 + hh) * S_ + s;
    float l = 0.f;
#pragma unroll
    for (int sp = 0; sp < NSPLIT; sp++) l += AccL[(size_t)sp * NBH * S_ + rowO];
    float inv = 1.0f / l;
    float a0 = 0.f, a1 = 0.f, a2 = 0.f;
#pragma unroll
    for (int half = 0; half < 2; half++) {
      float sum[8] = {};
#pragma unroll
      for (int sp = 0; sp < NSPLIT; sp++) {
        short8 v = *reinterpret_cast<const short8*>(&Ctx[sp * CTXSZ + rowO * 48 + 32 + half * 8]);
#pragma unroll
        for (int c = 0; c < 8; c++) sum[c] += f_of_bf16(v[c]);
      }
#pragma unroll
      for (int c = 0; c < 8; c++) {
        float val = sum[c] * inv;
        int j = hh * 16 + half * 8 + c;
        a0 += val * Wpo[j * 3 + 0];
        a1 += val * Wpo[j * 3 + 1];
        a2 += val * Wpo[j * 3 + 2];
      }
    }
    a0 += __shfl_xor(a0, 1); a0 += __shfl_xor(a0, 2); a0 += __shfl_xor(a0, 4);
    a1 += __shfl_xor(a1, 1); a1 += __shfl_xor(a1, 2); a1 += __shfl_xor(a1, 4);
    a2 += __shfl_xor(a2, 1); a2 += __shfl_xor(a2, 2); a2 += __shfl_xor(a2, 4);
    if (hh == 0) {
      float* po = Out + (size_t)MTOT * 256;
      po[(size_t)m * 3 + 0] = a0 + bpo[0];
      po[(size_t)m * 3 + 1] = a1 + bpo[1];
      po[(size_t)m * 3 + 2] = a2 + bpo[2];
    }
    return;
  }

  __shared__ __align__(16) short As[64 * 136];
  __shared__ __align__(16) short Bs[64 * 136];
  int n0 = blockIdx.y * 64;
  int lane = tid & 63, w = tid >> 6;
  int t = lane & 15, g = lane >> 4, kf = g * 8;
  int wm = w & 3, wn = w >> 2;
  f32x4 acc[2] = {};
  int srow = tid >> 3, skc = (tid & 7) * 16;
  for (int ph = 0; ph < 2; ph++) {
    int k0 = ph * 128;
    __syncthreads();
    {
      int kg = k0 + skc;
      int hh = kg >> 5, d0 = kg & 31;
      size_t rowO = (size_t)(b * 8 + hh) * S_ + sbase + srow;
      float l = 0.f;
#pragma unroll
      for (int sp = 0; sp < NSPLIT; sp++) l += AccL[(size_t)sp * NBH * S_ + rowO];
      float inv = 1.0f / l;
#pragma unroll
      for (int half = 0; half < 2; half++) {
        float sum[8] = {};
#pragma unroll
        for (int sp = 0; sp < NSPLIT; sp++) {
          short8 a = *reinterpret_cast<const short8*>(&Ctx[sp * CTXSZ + rowO * 48 + d0 + half * 8]);
#pragma unroll
          for (int c = 0; c < 8; c++) sum[c] += f_of_bf16(a[c]);
        }
        short8 o;
#pragma unroll
        for (int c = 0; c < 8; c++) o[c] = bf16_of(sum[c] * inv);
        *reinterpret_cast<short8*>(&As[srow * 136 + skc + half * 8]) = o;
      }
      *reinterpret_cast<uint4*>(&Bs[srow * 136 + skc]) =
          *reinterpret_cast<const uint4*>(&Wot[(size_t)(n0 + srow) * 256 + kg]);
      *reinterpret_cast<uint4*>(&Bs[srow * 136 + skc + 8]) =
          *reinterpret_cast<const uint4*>(&Wot[(size_t)(n0 + srow) * 256 + kg + 8]);
    }
    __syncthreads();
#pragma unroll
    for (int kk = 0; kk < 4; kk++) {
      short8 a = *reinterpret_cast<const short8*>(&As[(wm * 16 + t) * 136 + kk * 32 + kf]);
#pragma unroll
      for (int jj = 0; jj < 2; jj++) {
        short8 bb = *reinterpret_cast<const short8*>(&Bs[(wn * 32 + jj * 16 + t) * 136 + kk * 32 + kf]);
        acc[jj] = __builtin_amdgcn_mfma_f32_16x16x32_bf16(a, bb, acc[jj], 0, 0, 0);
      }
    }
  }
#pragma unroll
  for (int jj = 0; jj < 2; jj++)
#pragma unroll
    for (int r = 0; r < 4; r++) {
      int mrow = m0 + wm * 16 + g * 4 + r;
      int n = n0 + wn * 32 + jj * 16 + t;
      Out[(size_t)mrow * 256 + n] = acc[jj][r] + bo[n];
    }
}

// ---------------- launch ----------------

extern "C" void kernel_launch(void* const* d_in, const int* in_sizes, int n_in,
                              void* d_out, int out_size, void* d_ws, size_t ws_size,
                              hipStream_t stream) {
  const float* seq    = (const float*)d_in[0];
  const float* coords = (const float*)d_in[1];
  const int*   mask   = (const int*)d_in[3];
  const float* Wq  = (const float*)d_in[4];
  const float* bq  = (const float*)d_in[5];
  const float* Wk  = (const float*)d_in[6];
  const float* bk  = (const float*)d_in[7];
  const float* Wv  = (const float*)d_in[8];
  const float* bv  = (const float*)d_in[9];
  const float* Wpq = (const float*)d_in[10];
  const float* bpq = (const float*)d_in[11];
  const float* Wpk = (const float*)d_in[12];
  const float* bpk = (const float*)d_in[13];
  const float* Wo  = (const float*)d_in[14];
  const float* bo  = (const float*)d_in[15];
  const float* Wpo = (const float*)d_in[16];
  const float* bpo = (const float*)d_in[17];
  float* out = (float*)d_out;

  char* ws = (char*)d_ws;
  short* Wqkv_t = (short*)ws; ws += 768 * 256 * 2;
  short* Wo_t   = (short*)ws; ws += 256 * 256 * 2;
  short* Xb     = (short*)ws; ws += (size_t)MTOT * D_ * 2;
  short* Qa     = (short*)ws; ws += (size_t)NBH * S_ * AUGQ * 2;
  short* Ka     = (short*)ws; ws += (size_t)NBH * S_ * AUGQ * 2;
  short* VaT    = (short*)ws; ws += (size_t)NBH * 48 * S_ * 2;
  short* Ctx    = (short*)ws; ws += (size_t)NSPLIT * NBH * S_ * 48 * 2;
  float* AccL   = (float*)ws; ws += (size_t)NSPLIT * NBH * S_ * 4;

  prep_all<<<960, 256, 0, stream>>>(Wq, Wk, Wv, Wo, seq, coords, mask,
                                    Wpq, bpq, Wpk, bpk,
                                    Wqkv_t, Wo_t, Xb, Qa, Ka, VaT);
  qkv_gemm<<<dim3(64, 12), 256, 0, stream>>>(Xb, Wqkv_t, bq, bk, bv, Qa, Ka, VaT);
  attn<<<1024, 256, 0, stream>>>(Qa, Ka, VaT, Ctx, AccL);
  out_gemm<<<dim3(64, 5), 512, 0, stream>>>(Ctx, AccL, Wo_t, bo, Wpo, bpo, out);
}

// Round 13
// 74.825 us; speedup vs baseline: 1.1795x; 1.1795x over previous
//
#include <hip/hip_runtime.h>
#include <hip/hip_bf16.h>

#define D_ 256
#define H_ 8
#define B_ 2
#define S_ 2048
#define MTOT 4096
#define AUGQ 64          // q(32) + pq(16) + [maskbias](1) + pad(15)
#define NBH 16           // B_*H_
#define KPAD 72
#define NSPLIT 4
#define NJ 8             // key tiles (of 64) per split
#define LOG2E 1.4426950408889634f

typedef __attribute__((ext_vector_type(8))) short short8;
typedef __attribute__((ext_vector_type(4))) short short4v;
typedef __attribute__((ext_vector_type(4))) float f32x4;

static __device__ __forceinline__ short bf16_of(float f) {
  union { __hip_bfloat16 h; short s; } u;
  u.h = __float2bfloat16(f);
  return u.s;
}
static __device__ __forceinline__ float f_of_bf16(short s) {
  union { float f; unsigned int u; } u;
  u.u = ((unsigned int)(unsigned short)s) << 16;
  return u.f;
}

// key permutation within a 64-key tile: V column c holds key sinv(c)
static __device__ __forceinline__ int sinv64(int c) {
  return (((((c >> 2) & 1) << 1) | ((c >> 5) & 1)) << 4) + (((c >> 3) & 3) << 2) + (c & 3);
}

// ---------------- prep: sectioned by blockIdx ----------------

__global__ __launch_bounds__(256) void prep_all(
    const float* __restrict__ Wq, const float* __restrict__ Wk,
    const float* __restrict__ Wv, const float* __restrict__ Wo,
    const float* __restrict__ X, const float* __restrict__ coords,
    const int* __restrict__ mask,
    const float* __restrict__ Wpq, const float* __restrict__ bpq,
    const float* __restrict__ Wpk, const float* __restrict__ bpk,
    short* __restrict__ Wqkv_t, short* __restrict__ Wo_t,
    short* __restrict__ Xb,
    short* __restrict__ Qa, short* __restrict__ Ka, short* __restrict__ VaT) {
  int bid = blockIdx.x, tid = threadIdx.x;

  if (bid < 64) {
    __shared__ short T[64][72];
    const float* src;
    short* dst;
    int k0, n0g;
    if (bid < 48) {
      int nt = bid >> 2;
      k0 = (bid & 3) * 64;
      n0g = nt * 64;
      src = (n0g < 256) ? Wq : (n0g < 512 ? Wk : Wv);
      dst = Wqkv_t;
    } else {
      int t2 = bid - 48;
      k0 = (t2 & 3) * 64;
      n0g = (t2 >> 2) * 64;
      src = Wo;
      dst = Wo_t;
    }
    int ncol = n0g & 255;
    int rr = tid >> 4, cc = (tid & 15) * 4;
#pragma unroll
    for (int i = 0; i < 4; i++) {
      int r = rr + i * 16;
      f32x4 v = *reinterpret_cast<const f32x4*>(&src[(size_t)(k0 + r) * 256 + ncol + cc]);
      T[cc + 0][r] = bf16_of(v[0]);
      T[cc + 1][r] = bf16_of(v[1]);
      T[cc + 2][r] = bf16_of(v[2]);
      T[cc + 3][r] = bf16_of(v[3]);
    }
    __syncthreads();
    int n = tid >> 2, kk = (tid & 3) * 16;
    *reinterpret_cast<short8*>(&dst[(size_t)(n0g + n) * 256 + k0 + kk]) =
        *reinterpret_cast<const short8*>(&T[n][kk]);
    *reinterpret_cast<short8*>(&dst[(size_t)(n0g + n) * 256 + k0 + kk + 8]) =
        *reinterpret_cast<const short8*>(&T[n][kk + 8]);
    return;
  }

  if (bid < 576) {
    size_t i = (size_t)(bid - 64) * 2048 + tid * 8;
    f32x4 v0 = *reinterpret_cast<const f32x4*>(&X[i]);
    f32x4 v1 = *reinterpret_cast<const f32x4*>(&X[i + 4]);
    short8 o;
    o[0] = bf16_of(v0[0]); o[1] = bf16_of(v0[1]); o[2] = bf16_of(v0[2]); o[3] = bf16_of(v0[3]);
    o[4] = bf16_of(v1[0]); o[5] = bf16_of(v1[1]); o[6] = bf16_of(v1[2]); o[7] = bf16_of(v1[3]);
    *reinterpret_cast<short8*>(&Xb[i]) = o;
    return;
  }

  if (bid < 704) {
    int idx = (bid - 576) * 256 + tid;
    int m = idx >> 3, h = idx & 7;
    int b = m >> 11, s = m & 2047;
    float r0 = coords[m * 9 + 3], r1 = coords[m * 9 + 4], r2 = coords[m * 9 + 5];
    size_t base = ((size_t)(b * 8 + h) * S_ + s) * AUGQ;
    short8 pqv[2], pkv[2];
#pragma unroll
    for (int c = 0; c < 2; c++)
#pragma unroll
      for (int i = 0; i < 8; i++) {
        int j = h * 16 + c * 8 + i;
        float pq = r0 * Wpq[j] + r1 * Wpq[128 + j] + r2 * Wpq[256 + j] + bpq[j];
        float pk = r0 * Wpk[j] + r1 * Wpk[128 + j] + r2 * Wpk[256 + j] + bpk[j];
        pqv[c][i] = bf16_of(pq * LOG2E);
        pkv[c][i] = bf16_of(pk * 0.25f);
      }
    short8 padq = {};
    padq[0] = bf16_of(LOG2E);
    short8 padk = {};
    padk[0] = mask[m] ? (short)0 : bf16_of(-1e9f);
    short8 z = {};
    *reinterpret_cast<short8*>(&Qa[base + 32]) = pqv[0];
    *reinterpret_cast<short8*>(&Qa[base + 40]) = pqv[1];
    *reinterpret_cast<short8*>(&Qa[base + 48]) = padq;
    *reinterpret_cast<short8*>(&Qa[base + 56]) = z;
    *reinterpret_cast<short8*>(&Ka[base + 32]) = pkv[0];
    *reinterpret_cast<short8*>(&Ka[base + 40]) = pkv[1];
    *reinterpret_cast<short8*>(&Ka[base + 48]) = padk;
    *reinterpret_cast<short8*>(&Ka[base + 56]) = z;
    return;
  }

  {
    int idx = (bid - 704) * 256 + tid;
    int s8 = idx & 255, p = (idx >> 8) & 15, bh = idx >> 12;
    int b = bh >> 3, h = bh & 7, j = h * 16 + p;
    float w0 = Wpq[j], w1 = Wpq[128 + j], w2 = Wpq[256 + j], bb = bpq[j];
    short8 o;
#pragma unroll
    for (int i = 0; i < 8; i++) {
      int c = (s8 & 7) * 8 + i;
      int m = b * 2048 + (s8 >> 3) * 64 + sinv64(c);
      o[i] = bf16_of(coords[m * 9 + 3] * w0 + coords[m * 9 + 4] * w1 +
                     coords[m * 9 + 5] * w2 + bb);
    }
    *reinterpret_cast<short8*>(&VaT[((size_t)bh * 48 + 32 + p) * S_ + s8 * 8]) = o;
  }
}

// ---------------- QKV GEMM: 128x128 tile, BK=64, reg-staged, 4x4 acc/wave ----------------
// grid (32, 6); 256 threads = 4 waves, each wave owns a 64x64 quadrant.
// LDS: As[128][72] @0 (18432B), Bs[128][72] @18432. Epilogue overlays Cs[128][136].

__global__ __launch_bounds__(256) void qkv_gemm(
    const short* __restrict__ Xb, const short* __restrict__ Wt,
    const float* __restrict__ bq, const float* __restrict__ bk, const float* __restrict__ bv,
    short* __restrict__ Qa, short* __restrict__ Ka, short* __restrict__ VaT) {
  __shared__ __align__(16) char smem[36864];
  short* As = (short*)smem;              // [128][72]
  short* Bs = (short*)(smem + 18432);    // [128][72]
  int m0 = blockIdx.x * 128, n0 = blockIdx.y * 128;
  int tid = threadIdx.x, lane = tid & 63, w = tid >> 6;
  int t = lane & 15, g = lane >> 4, kf = g * 8;
  int wr = (w >> 1) * 64, wc = (w & 1) * 64;
  f32x4 acc[4][4] = {};
  int srow = tid >> 1, shalf = (tid & 1) * 32;   // row 0..127, 32-short half
  for (int k0 = 0; k0 < 256; k0 += 64) {
    // stage to regs (loads in flight across the barrier)
    uint4 aR[4], bR[4];
    {
      const uint4* ga = reinterpret_cast<const uint4*>(&Xb[(size_t)(m0 + srow) * 256 + k0 + shalf]);
      const uint4* gb = reinterpret_cast<const uint4*>(&Wt[(size_t)(n0 + srow) * 256 + k0 + shalf]);
#pragma unroll
      for (int i = 0; i < 4; i++) aR[i] = ga[i];
#pragma unroll
      for (int i = 0; i < 4; i++) bR[i] = gb[i];
    }
    __syncthreads();   // all waves done reading LDS from previous phase
#pragma unroll
    for (int i = 0; i < 4; i++)
      *reinterpret_cast<uint4*>(&As[srow * 72 + shalf + i * 8]) = aR[i];
#pragma unroll
    for (int i = 0; i < 4; i++)
      *reinterpret_cast<uint4*>(&Bs[srow * 72 + shalf + i * 8]) = bR[i];
    __syncthreads();
#pragma unroll
    for (int kk = 0; kk < 2; kk++) {
      short8 a[4], bb[4];
#pragma unroll
      for (int i = 0; i < 4; i++)
        a[i] = *reinterpret_cast<const short8*>(&As[(wr + i * 16 + t) * 72 + kk * 32 + kf]);
#pragma unroll
      for (int j = 0; j < 4; j++)
        bb[j] = *reinterpret_cast<const short8*>(&Bs[(wc + j * 16 + t) * 72 + kk * 32 + kf]);
#pragma unroll
      for (int i = 0; i < 4; i++)
#pragma unroll
        for (int j = 0; j < 4; j++)
          acc[i][j] = __builtin_amdgcn_mfma_f32_16x16x32_bf16(a[i], bb[j], acc[i][j], 0, 0, 0);
    }
  }
  // epilogue: bias/scale -> Cs[128][136] bf16 -> vector scatter
  __syncthreads();
  short* Cs = (short*)smem;
  const float scale = 0.17677669529663687f * LOG2E;
  int b = m0 >> 11, sbase = m0 & 2047;
#pragma unroll
  for (int i = 0; i < 4; i++)
#pragma unroll
    for (int j = 0; j < 4; j++)
#pragma unroll
      for (int r = 0; r < 4; r++) {
        int rl = wr + i * 16 + g * 4 + r;
        int cl = wc + j * 16 + t;
        int n = n0 + cl;
        float v = acc[i][j][r];
        if (n < 256) v = (v + bq[n]) * scale;
        else if (n < 512) v = v + bk[n - 256];
        else v = v + bv[n - 512];
        Cs[rl * 136 + cl] = bf16_of(v);
      }
  __syncthreads();
  if (n0 < 512) {
#pragma unroll
    for (int i2 = 0; i2 < 8; i2++) {
      int task = tid + i2 * 256;           // 2048 tasks
      int row = task >> 4, c = task & 15;
      int n = n0 + c * 8;
      short* dst = (n < 256) ? Qa : Ka;
      int nn = n & 255;
      int hh = nn >> 5, d = nn & 31;
      *reinterpret_cast<short8*>(&dst[((size_t)(b * 8 + hh) * S_ + sbase + row) * AUGQ + d]) =
          *reinterpret_cast<const short8*>(&Cs[row * 136 + c * 8]);
    }
  } else {
    int hv0 = (n0 - 512) >> 5;
#pragma unroll
    for (int i2 = 0; i2 < 8; i2++) {
      int task = tid + i2 * 256;           // 2048 tasks
      int fl = task >> 4, sc = task & 15;
      int h64 = sc >> 3, c8 = sc & 7;
      short8 o;
#pragma unroll
      for (int i = 0; i < 8; i++)
        o[i] = Cs[(h64 * 64 + sinv64(c8 * 8 + i)) * 136 + fl];
      int hh = hv0 + (fl >> 5), d = fl & 31;
      *reinterpret_cast<short8*>(
          &VaT[((size_t)(b * 8 + hh) * 48 + d) * S_ + sbase + h64 * 64 + c8 * 8]) = o;
    }
  }
}

// ---------------- flash attention: swapped QK^T, register P, K=32 PV (R9-proven) ----------------

__global__ __launch_bounds__(256, 4) void attn(
    const short* __restrict__ Qa, const short* __restrict__ Ka,
    const short* __restrict__ VaT,
    short* __restrict__ Ctx, float* __restrict__ AccL) {
  __shared__ __align__(16) char smem[32256];

  int bid = blockIdx.x;
  int xcd = bid & 7, slot = bid >> 3;
  int gidx = xcd * 8 + (slot >> 4);
  int it = slot & 15;
  int split = gidx & 3;
  int bhv = gidx >> 2;

  int tid = threadIdx.x, lane = tid & 63, w = tid >> 6;
  int t = lane & 15, g = lane >> 4, kf = g * 8;
  int q0w = it * 128 + w * 32;
  size_t bh = (size_t)bhv * S_;

  short8 aq[2][2];
#pragma unroll
  for (int g2 = 0; g2 < 2; g2++)
#pragma unroll
    for (int c = 0; c < 2; c++)
      aq[g2][c] = *reinterpret_cast<const short8*>(
          &Qa[(bh + q0w + g2 * 16 + t) * AUGQ + c * 32 + kf]);

  f32x4 OaccA[3] = {}, OaccB[3] = {};
  float lsum0 = 0.f, lsum1 = 0.f;

  uint4 kreg0, kreg1, vreg0, vreg1;
  int srow = tid >> 3, sko = (tid & 7) * 8;
  const int jt0 = split * NJ;

  auto issue = [&](int jt) {
    const uint4* ks = reinterpret_cast<const uint4*>(&Ka[(bh + jt * 64) * AUGQ]);
    kreg0 = ks[tid];
    kreg1 = ks[tid + 256];
    size_t vb = (size_t)bhv * 48 * S_ + jt * 64;
    vreg0 = *reinterpret_cast<const uint4*>(&VaT[vb + (size_t)srow * S_ + sko]);
    if (tid < 128)
      vreg1 = *reinterpret_cast<const uint4*>(&VaT[vb + (size_t)(srow + 32) * S_ + sko]);
  };
  auto commit = [&](int buf) {
    short* Kd = (short*)(smem + buf * 9216);
    short* Vd = (short*)(smem + 18432 + buf * 6912);
    *reinterpret_cast<uint4*>(&Kd[srow * KPAD + sko]) = kreg0;
    *reinterpret_cast<uint4*>(&Kd[(srow + 32) * KPAD + sko]) = kreg1;
    *reinterpret_cast<uint4*>(&Vd[srow * KPAD + sko]) = vreg0;
    if (tid < 128)
      *reinterpret_cast<uint4*>(&Vd[(srow + 32) * KPAD + sko]) = vreg1;
  };

  issue(jt0);
  commit(0);
  __syncthreads();

  for (int j = 0; j < NJ; j++) {
    int cur = j & 1;
    if (j + 1 < NJ) issue(jt0 + j + 1);
    const short* Kc = (const short*)(smem + cur * 9216);
    const short* Vc = (const short*)(smem + 18432 + cur * 6912);
    short8 pA[2], pB[2];
#pragma unroll
    for (int sub = 0; sub < 4; sub++) {
      short8 ka0 = *reinterpret_cast<const short8*>(&Kc[(sub * 16 + t) * KPAD + kf]);
      short8 ka1 = *reinterpret_cast<const short8*>(&Kc[(sub * 16 + t) * KPAD + 32 + kf]);
      f32x4 sA = {}, sB = {};
      sA = __builtin_amdgcn_mfma_f32_16x16x32_bf16(ka0, aq[0][0], sA, 0, 0, 0);
      sA = __builtin_amdgcn_mfma_f32_16x16x32_bf16(ka1, aq[0][1], sA, 0, 0, 0);
      sB = __builtin_amdgcn_mfma_f32_16x16x32_bf16(ka0, aq[1][0], sB, 0, 0, 0);
      sB = __builtin_amdgcn_mfma_f32_16x16x32_bf16(ka1, aq[1][1], sB, 0, 0, 0);
      float a0 = exp2f(sA[0]), a1 = exp2f(sA[1]), a2 = exp2f(sA[2]), a3 = exp2f(sA[3]);
      float b0 = exp2f(sB[0]), b1 = exp2f(sB[1]), b2 = exp2f(sB[2]), b3 = exp2f(sB[3]);
      lsum0 += (a0 + a1) + (a2 + a3);
      lsum1 += (b0 + b1) + (b2 + b3);
      int ww = sub & 1, off = (sub >> 1) * 4;
      pA[ww][off + 0] = bf16_of(a0); pA[ww][off + 1] = bf16_of(a1);
      pA[ww][off + 2] = bf16_of(a2); pA[ww][off + 3] = bf16_of(a3);
      pB[ww][off + 0] = bf16_of(b0); pB[ww][off + 1] = bf16_of(b1);
      pB[ww][off + 2] = bf16_of(b2); pB[ww][off + 3] = bf16_of(b3);
    }
    __builtin_amdgcn_s_setprio(1);
#pragma unroll
    for (int tt = 0; tt < 3; tt++) {
#pragma unroll
      for (int w2 = 0; w2 < 2; w2++) {
        short8 va = *reinterpret_cast<const short8*>(&Vc[(tt * 16 + t) * KPAD + w2 * 32 + kf]);
        OaccA[tt] = __builtin_amdgcn_mfma_f32_16x16x32_bf16(va, pA[w2], OaccA[tt], 0, 0, 0);
        OaccB[tt] = __builtin_amdgcn_mfma_f32_16x16x32_bf16(va, pB[w2], OaccB[tt], 0, 0, 0);
      }
    }
    __builtin_amdgcn_s_setprio(0);
    if (j + 1 < NJ) commit(cur ^ 1);
    __syncthreads();
  }

  lsum0 += __shfl_xor(lsum0, 16); lsum0 += __shfl_xor(lsum0, 32);
  lsum1 += __shfl_xor(lsum1, 16); lsum1 += __shfl_xor(lsum1, 32);

  float* Of = (float*)smem;
#pragma unroll
  for (int tt = 0; tt < 3; tt++)
#pragma unroll
    for (int r = 0; r < 4; r++) {
      Of[(w * 32 + t) * 52 + tt * 16 + g * 4 + r] = OaccA[tt][r];
      Of[(w * 32 + 16 + t) * 52 + tt * 16 + g * 4 + r] = OaccB[tt][r];
    }
  if (lane < 16) {
    size_t lb = (size_t)(split * NBH + bhv) * S_ + q0w + lane;
    AccL[lb] = lsum0;
    AccL[lb + 16] = lsum1;
  }
  __syncthreads();
  short* CtxP = Ctx + (size_t)split * NBH * S_ * 48;
  size_t obase = bh + it * 128;
  for (int task = tid; task < 768; task += 256) {
    int row = task / 6, c8 = task % 6;
    const float* src = &Of[row * 52 + c8 * 8];
    short8 o;
#pragma unroll
    for (int i = 0; i < 8; i++) o[i] = bf16_of(src[i]);
    *reinterpret_cast<short8*>(&CtxP[(obase + row) * 48 + c8 * 8]) = o;
  }
}

// ---------------- output projection + fused 4-way split-merge + fused point_proj ----------------

__global__ __launch_bounds__(512) void out_gemm(
    const short* __restrict__ Ctx, const float* __restrict__ AccL,
    const short* __restrict__ Wot, const float* __restrict__ bo,
    const float* __restrict__ Wpo, const float* __restrict__ bpo,
    float* __restrict__ Out) {
  const size_t CTXSZ = (size_t)NBH * S_ * 48;
  int m0 = blockIdx.x * 64;
  int tid = threadIdx.x;
  int b = m0 >> 11, sbase = m0 & 2047;

  if (blockIdx.y == 4) {
    int row = tid >> 3, hh = tid & 7;
    int m = m0 + row, s = sbase + row;
    size_t rowO = (size_t)(b * 8 + hh) * S_ + s;
    float l = 0.f;
#pragma unroll
    for (int sp = 0; sp < NSPLIT; sp++) l += AccL[(size_t)sp * NBH * S_ + rowO];
    float inv = 1.0f / l;
    float a0 = 0.f, a1 = 0.f, a2 = 0.f;
#pragma unroll
    for (int half = 0; half < 2; half++) {
      float sum[8] = {};
#pragma unroll
      for (int sp = 0; sp < NSPLIT; sp++) {
        short8 v = *reinterpret_cast<const short8*>(&Ctx[sp * CTXSZ + rowO * 48 + 32 + half * 8]);
#pragma unroll
        for (int c = 0; c < 8; c++) sum[c] += f_of_bf16(v[c]);
      }
#pragma unroll
      for (int c = 0; c < 8; c++) {
        float val = sum[c] * inv;
        int j = hh * 16 + half * 8 + c;
        a0 += val * Wpo[j * 3 + 0];
        a1 += val * Wpo[j * 3 + 1];
        a2 += val * Wpo[j * 3 + 2];
      }
    }
    a0 += __shfl_xor(a0, 1); a0 += __shfl_xor(a0, 2); a0 += __shfl_xor(a0, 4);
    a1 += __shfl_xor(a1, 1); a1 += __shfl_xor(a1, 2); a1 += __shfl_xor(a1, 4);
    a2 += __shfl_xor(a2, 1); a2 += __shfl_xor(a2, 2); a2 += __shfl_xor(a2, 4);
    if (hh == 0) {
      float* po = Out + (size_t)MTOT * 256;
      po[(size_t)m * 3 + 0] = a0 + bpo[0];
      po[(size_t)m * 3 + 1] = a1 + bpo[1];
      po[(size_t)m * 3 + 2] = a2 + bpo[2];
    }
    return;
  }

  __shared__ __align__(16) short As[64 * 136];
  __shared__ __align__(16) short Bs[64 * 136];
  int n0 = blockIdx.y * 64;
  int lane = tid & 63, w = tid >> 6;
  int t = lane & 15, g = lane >> 4, kf = g * 8;
  int wm = w & 3, wn = w >> 2;
  f32x4 acc[2] = {};
  int srow = tid >> 3, skc = (tid & 7) * 16;
  for (int ph = 0; ph < 2; ph++) {
    int k0 = ph * 128;
    __syncthreads();
    {
      int kg = k0 + skc;
      int hh = kg >> 5, d0 = kg & 31;
      size_t rowO = (size_t)(b * 8 + hh) * S_ + sbase + srow;
      float l = 0.f;
#pragma unroll
      for (int sp = 0; sp < NSPLIT; sp++) l += AccL[(size_t)sp * NBH * S_ + rowO];
      float inv = 1.0f / l;
#pragma unroll
      for (int half = 0; half < 2; half++) {
        float sum[8] = {};
#pragma unroll
        for (int sp = 0; sp < NSPLIT; sp++) {
          short8 a = *reinterpret_cast<const short8*>(&Ctx[sp * CTXSZ + rowO * 48 + d0 + half * 8]);
#pragma unroll
          for (int c = 0; c < 8; c++) sum[c] += f_of_bf16(a[c]);
        }
        short8 o;
#pragma unroll
        for (int c = 0; c < 8; c++) o[c] = bf16_of(sum[c] * inv);
        *reinterpret_cast<short8*>(&As[srow * 136 + skc + half * 8]) = o;
      }
      *reinterpret_cast<uint4*>(&Bs[srow * 136 + skc]) =
          *reinterpret_cast<const uint4*>(&Wot[(size_t)(n0 + srow) * 256 + kg]);
      *reinterpret_cast<uint4*>(&Bs[srow * 136 + skc + 8]) =
          *reinterpret_cast<const uint4*>(&Wot[(size_t)(n0 + srow) * 256 + kg + 8]);
    }
    __syncthreads();
#pragma unroll
    for (int kk = 0; kk < 4; kk++) {
      short8 a = *reinterpret_cast<const short8*>(&As[(wm * 16 + t) * 136 + kk * 32 + kf]);
#pragma unroll
      for (int jj = 0; jj < 2; jj++) {
        short8 bb = *reinterpret_cast<const short8*>(&Bs[(wn * 32 + jj * 16 + t) * 136 + kk * 32 + kf]);
        acc[jj] = __builtin_amdgcn_mfma_f32_16x16x32_bf16(a, bb, acc[jj], 0, 0, 0);
      }
    }
  }
#pragma unroll
  for (int jj = 0; jj < 2; jj++)
#pragma unroll
    for (int r = 0; r < 4; r++) {
      int mrow = m0 + wm * 16 + g * 4 + r;
      int n = n0 + wn * 32 + jj * 16 + t;
      Out[(size_t)mrow * 256 + n] = acc[jj][r] + bo[n];
    }
}

// ---------------- launch ----------------

extern "C" void kernel_launch(void* const* d_in, const int* in_sizes, int n_in,
                              void* d_out, int out_size, void* d_ws, size_t ws_size,
                              hipStream_t stream) {
  const float* seq    = (const float*)d_in[0];
  const float* coords = (const float*)d_in[1];
  const int*   mask   = (const int*)d_in[3];
  const float* Wq  = (const float*)d_in[4];
  const float* bq  = (const float*)d_in[5];
  const float* Wk  = (const float*)d_in[6];
  const float* bk  = (const float*)d_in[7];
  const float* Wv  = (const float*)d_in[8];
  const float* bv  = (const float*)d_in[9];
  const float* Wpq = (const float*)d_in[10];
  const float* bpq = (const float*)d_in[11];
  const float* Wpk = (const float*)d_in[12];
  const float* bpk = (const float*)d_in[13];
  const float* Wo  = (const float*)d_in[14];
  const float* bo  = (const float*)d_in[15];
  const float* Wpo = (const float*)d_in[16];
  const float* bpo = (const float*)d_in[17];
  float* out = (float*)d_out;

  char* ws = (char*)d_ws;
  short* Wqkv_t = (short*)ws; ws += 768 * 256 * 2;
  short* Wo_t   = (short*)ws; ws += 256 * 256 * 2;
  short* Xb     = (short*)ws; ws += (size_t)MTOT * D_ * 2;
  short* Qa     = (short*)ws; ws += (size_t)NBH * S_ * AUGQ * 2;
  short* Ka     = (short*)ws; ws += (size_t)NBH * S_ * AUGQ * 2;
  short* VaT    = (short*)ws; ws += (size_t)NBH * 48 * S_ * 2;
  short* Ctx    = (short*)ws; ws += (size_t)NSPLIT * NBH * S_ * 48 * 2;
  float* AccL   = (float*)ws; ws += (size_t)NSPLIT * NBH * S_ * 4;

  prep_all<<<960, 256, 0, stream>>>(Wq, Wk, Wv, Wo, seq, coords, mask,
                                    Wpq, bpq, Wpk, bpk,
                                    Wqkv_t, Wo_t, Xb, Qa, Ka, VaT);
  qkv_gemm<<<dim3(32, 6), 256, 0, stream>>>(Xb, Wqkv_t, bq, bk, bv, Qa, Ka, VaT);
  attn<<<1024, 256, 0, stream>>>(Qa, Ka, VaT, Ctx, AccL);
  out_gemm<<<dim3(64, 5), 512, 0, stream>>>(Ctx, AccL, Wo_t, bo, Wpo, bpo, out);
}

// Round 14
// 60.647 us; speedup vs baseline: 1.4552x; 1.2338x over previous
//
#include <hip/hip_runtime.h>
#include <hip/hip_bf16.h>

#define D_ 256
#define H_ 8
#define B_ 2
#define S_ 2048
#define MTOT 4096
#define AUGQ 64          // q(32) + pq(16) + [maskbias](1) + pad(15)
#define NBH 16           // B_*H_
#define KPAD 72
#define NSPLIT 4
#define NJ 8             // key tiles (of 64) per split
#define LOG2E 1.4426950408889634f

typedef __attribute__((ext_vector_type(8))) short short8;
typedef __attribute__((ext_vector_type(4))) short short4v;
typedef __attribute__((ext_vector_type(4))) float f32x4;

static __device__ __forceinline__ short bf16_of(float f) {
  union { __hip_bfloat16 h; short s; } u;
  u.h = __float2bfloat16(f);
  return u.s;
}
static __device__ __forceinline__ float f_of_bf16(short s) {
  union { float f; unsigned int u; } u;
  u.u = ((unsigned int)(unsigned short)s) << 16;
  return u.f;
}

// key permutation within a 64-key tile: V column c holds key sinv(c)
static __device__ __forceinline__ int sinv64(int c) {
  return (((((c >> 2) & 1) << 1) | ((c >> 5) & 1)) << 4) + (((c >> 3) & 3) << 2) + (c & 3);
}

// ---------------- prep: sectioned by blockIdx ----------------

__global__ __launch_bounds__(256) void prep_all(
    const float* __restrict__ Wq, const float* __restrict__ Wk,
    const float* __restrict__ Wv, const float* __restrict__ Wo,
    const float* __restrict__ X, const float* __restrict__ coords,
    const int* __restrict__ mask,
    const float* __restrict__ Wpq, const float* __restrict__ bpq,
    const float* __restrict__ Wpk, const float* __restrict__ bpk,
    short* __restrict__ Wqkv_t, short* __restrict__ Wo_t,
    short* __restrict__ Xb,
    short* __restrict__ Qa, short* __restrict__ Ka, short* __restrict__ VaT) {
  int bid = blockIdx.x, tid = threadIdx.x;

  if (bid < 64) {
    __shared__ short T[64][72];
    const float* src;
    short* dst;
    int k0, n0g;
    if (bid < 48) {
      int nt = bid >> 2;
      k0 = (bid & 3) * 64;
      n0g = nt * 64;
      src = (n0g < 256) ? Wq : (n0g < 512 ? Wk : Wv);
      dst = Wqkv_t;
    } else {
      int t2 = bid - 48;
      k0 = (t2 & 3) * 64;
      n0g = (t2 >> 2) * 64;
      src = Wo;
      dst = Wo_t;
    }
    int ncol = n0g & 255;
    int rr = tid >> 4, cc = (tid & 15) * 4;
#pragma unroll
    for (int i = 0; i < 4; i++) {
      int r = rr + i * 16;
      f32x4 v = *reinterpret_cast<const f32x4*>(&src[(size_t)(k0 + r) * 256 + ncol + cc]);
      T[cc + 0][r] = bf16_of(v[0]);
      T[cc + 1][r] = bf16_of(v[1]);
      T[cc + 2][r] = bf16_of(v[2]);
      T[cc + 3][r] = bf16_of(v[3]);
    }
    __syncthreads();
    int n = tid >> 2, kk = (tid & 3) * 16;
    *reinterpret_cast<short8*>(&dst[(size_t)(n0g + n) * 256 + k0 + kk]) =
        *reinterpret_cast<const short8*>(&T[n][kk]);
    *reinterpret_cast<short8*>(&dst[(size_t)(n0g + n) * 256 + k0 + kk + 8]) =
        *reinterpret_cast<const short8*>(&T[n][kk + 8]);
    return;
  }

  if (bid < 576) {
    size_t i = (size_t)(bid - 64) * 2048 + tid * 8;
    f32x4 v0 = *reinterpret_cast<const f32x4*>(&X[i]);
    f32x4 v1 = *reinterpret_cast<const f32x4*>(&X[i + 4]);
    short8 o;
    o[0] = bf16_of(v0[0]); o[1] = bf16_of(v0[1]); o[2] = bf16_of(v0[2]); o[3] = bf16_of(v0[3]);
    o[4] = bf16_of(v1[0]); o[5] = bf16_of(v1[1]); o[6] = bf16_of(v1[2]); o[7] = bf16_of(v1[3]);
    *reinterpret_cast<short8*>(&Xb[i]) = o;
    return;
  }

  if (bid < 704) {
    int idx = (bid - 576) * 256 + tid;
    int m = idx >> 3, h = idx & 7;
    int b = m >> 11, s = m & 2047;
    float r0 = coords[m * 9 + 3], r1 = coords[m * 9 + 4], r2 = coords[m * 9 + 5];
    size_t base = ((size_t)(b * 8 + h) * S_ + s) * AUGQ;
    short8 pqv[2], pkv[2];
#pragma unroll
    for (int c = 0; c < 2; c++)
#pragma unroll
      for (int i = 0; i < 8; i++) {
        int j = h * 16 + c * 8 + i;
        float pq = r0 * Wpq[j] + r1 * Wpq[128 + j] + r2 * Wpq[256 + j] + bpq[j];
        float pk = r0 * Wpk[j] + r1 * Wpk[128 + j] + r2 * Wpk[256 + j] + bpk[j];
        pqv[c][i] = bf16_of(pq * LOG2E);
        pkv[c][i] = bf16_of(pk * 0.25f);
      }
    short8 padq = {};
    padq[0] = bf16_of(LOG2E);
    short8 padk = {};
    padk[0] = mask[m] ? (short)0 : bf16_of(-1e9f);
    short8 z = {};
    *reinterpret_cast<short8*>(&Qa[base + 32]) = pqv[0];
    *reinterpret_cast<short8*>(&Qa[base + 40]) = pqv[1];
    *reinterpret_cast<short8*>(&Qa[base + 48]) = padq;
    *reinterpret_cast<short8*>(&Qa[base + 56]) = z;
    *reinterpret_cast<short8*>(&Ka[base + 32]) = pkv[0];
    *reinterpret_cast<short8*>(&Ka[base + 40]) = pkv[1];
    *reinterpret_cast<short8*>(&Ka[base + 48]) = padk;
    *reinterpret_cast<short8*>(&Ka[base + 56]) = z;
    return;
  }

  {
    int idx = (bid - 704) * 256 + tid;
    int s8 = idx & 255, p = (idx >> 8) & 15, bh = idx >> 12;
    int b = bh >> 3, h = bh & 7, j = h * 16 + p;
    float w0 = Wpq[j], w1 = Wpq[128 + j], w2 = Wpq[256 + j], bb = bpq[j];
    short8 o;
#pragma unroll
    for (int i = 0; i < 8; i++) {
      int c = (s8 & 7) * 8 + i;
      int m = b * 2048 + (s8 >> 3) * 64 + sinv64(c);
      o[i] = bf16_of(coords[m * 9 + 3] * w0 + coords[m * 9 + 4] * w1 +
                     coords[m * 9 + 5] * w2 + bb);
    }
    *reinterpret_cast<short8*>(&VaT[((size_t)bh * 48 + 32 + p) * S_ + s8 * 8]) = o;
  }
}

// ---------------- QKV GEMM (M=4096, N=768, K=256), 64x64 tile (768 blocks, 3/CU) ----------------

__global__ __launch_bounds__(256) void qkv_gemm(
    const short* __restrict__ Xb, const short* __restrict__ Wt,
    const float* __restrict__ bq, const float* __restrict__ bk, const float* __restrict__ bv,
    short* __restrict__ Qa, short* __restrict__ Ka, short* __restrict__ VaT) {
  __shared__ __align__(16) short As[64 * 136];
  __shared__ __align__(16) short Bs[64 * 136];
  int m0 = blockIdx.x * 64, n0 = blockIdx.y * 64;
  int tid = threadIdx.x, lane = tid & 63, w = tid >> 6;
  int t = lane & 15, g = lane >> 4, kf = g * 8;
  int wr = (w >> 1) * 32, wc = (w & 1) * 32;
  f32x4 acc[2][2] = {};
  int srow = tid >> 2, skc = (tid & 3) * 32;
  for (int ph = 0; ph < 2; ph++) {
    int k0 = ph * 128;
    __syncthreads();
    {
      const uint4* xsrc = reinterpret_cast<const uint4*>(&Xb[(size_t)(m0 + srow) * 256 + k0 + skc]);
      const uint4* wsrc = reinterpret_cast<const uint4*>(&Wt[(size_t)(n0 + srow) * 256 + k0 + skc]);
#pragma unroll
      for (int i = 0; i < 4; i++)
        *reinterpret_cast<uint4*>(&As[srow * 136 + skc + i * 8]) = xsrc[i];
#pragma unroll
      for (int i = 0; i < 4; i++)
        *reinterpret_cast<uint4*>(&Bs[srow * 136 + skc + i * 8]) = wsrc[i];
    }
    __syncthreads();
#pragma unroll
    for (int kk = 0; kk < 4; kk++) {
      short8 a[2], bb[2];
#pragma unroll
      for (int i = 0; i < 2; i++)
        a[i] = *reinterpret_cast<const short8*>(&As[(wr + i * 16 + t) * 136 + kk * 32 + kf]);
#pragma unroll
      for (int jj = 0; jj < 2; jj++)
        bb[jj] = *reinterpret_cast<const short8*>(&Bs[(wc + jj * 16 + t) * 136 + kk * 32 + kf]);
#pragma unroll
      for (int i = 0; i < 2; i++)
#pragma unroll
        for (int jj = 0; jj < 2; jj++)
          acc[i][jj] = __builtin_amdgcn_mfma_f32_16x16x32_bf16(a[i], bb[jj], acc[i][jj], 0, 0, 0);
    }
  }
  __syncthreads();
  short* Cs = As;
  const float scale = 0.17677669529663687f * LOG2E;  // (1/sqrt(32)) * log2e
  int b = m0 >> 11, sbase = m0 & 2047;
#pragma unroll
  for (int i = 0; i < 2; i++)
#pragma unroll
    for (int jj = 0; jj < 2; jj++)
#pragma unroll
      for (int r = 0; r < 4; r++) {
        int rl = wr + i * 16 + g * 4 + r;
        int cl = wc + jj * 16 + t;
        int n = n0 + cl;
        float v = acc[i][jj][r];
        if (n < 256) v = (v + bq[n]) * scale;
        else if (n < 512) v = v + bk[n - 256];
        else v = v + bv[n - 512];
        Cs[rl * 72 + cl] = bf16_of(v);
      }
  __syncthreads();
  if (n0 < 512) {
#pragma unroll
    for (int i2 = 0; i2 < 2; i2++) {
      int task = tid + i2 * 256;
      int row = task >> 3, c = task & 7;
      int n = n0 + c * 8;
      short* dst = (n < 256) ? Qa : Ka;
      int nn = n & 255;
      int hh = nn >> 5, d = nn & 31;
      *reinterpret_cast<short8*>(&dst[((size_t)(b * 8 + hh) * S_ + sbase + row) * AUGQ + d]) =
          *reinterpret_cast<const short8*>(&Cs[row * 72 + c * 8]);
    }
  } else {
    int hv0 = (n0 - 512) >> 5;
#pragma unroll
    for (int i2 = 0; i2 < 2; i2++) {
      int task = tid + i2 * 256;
      int fl = task >> 3, s8 = task & 7;
      short8 o;
#pragma unroll
      for (int i = 0; i < 8; i++) o[i] = Cs[sinv64(s8 * 8 + i) * 72 + fl];
      int hh = hv0 + (fl >> 5), d = fl & 31;
      *reinterpret_cast<short8*>(&VaT[((size_t)(b * 8 + hh) * 48 + d) * S_ + sbase + s8 * 8]) = o;
    }
  }
}

// ---------------- flash attention: swapped QK^T, register P, K=32 PV ----------------
// grid 1024 (XCD-swizzled, 4 blocks/CU); block 256 = 4 waves, each wave 32 queries.
// Double-buffered LDS; commit of next tile overlaps the PV MFMA cluster.

__global__ __launch_bounds__(256, 4) void attn(
    const short* __restrict__ Qa, const short* __restrict__ Ka,
    const short* __restrict__ VaT,
    short* __restrict__ Ctx, float* __restrict__ AccL) {
  __shared__ __align__(16) char smem[32256];

  int bid = blockIdx.x;
  int xcd = bid & 7, slot = bid >> 3;
  int gidx = xcd * 8 + (slot >> 4);
  int it = slot & 15;
  int split = gidx & 3;
  int bhv = gidx >> 2;

  int tid = threadIdx.x, lane = tid & 63, w = tid >> 6;
  int t = lane & 15, g = lane >> 4, kf = g * 8;
  int q0w = it * 128 + w * 32;
  size_t bh = (size_t)bhv * S_;

  short8 aq[2][2];
#pragma unroll
  for (int g2 = 0; g2 < 2; g2++)
#pragma unroll
    for (int c = 0; c < 2; c++)
      aq[g2][c] = *reinterpret_cast<const short8*>(
          &Qa[(bh + q0w + g2 * 16 + t) * AUGQ + c * 32 + kf]);

  f32x4 OaccA[3] = {}, OaccB[3] = {};
  float lsum0 = 0.f, lsum1 = 0.f;

  uint4 kreg0, kreg1, vreg0, vreg1;
  int srow = tid >> 3, sko = (tid & 7) * 8;
  const int jt0 = split * NJ;

  auto issue = [&](int jt) {
    const uint4* ks = reinterpret_cast<const uint4*>(&Ka[(bh + jt * 64) * AUGQ]);
    kreg0 = ks[tid];
    kreg1 = ks[tid + 256];
    size_t vb = (size_t)bhv * 48 * S_ + jt * 64;
    vreg0 = *reinterpret_cast<const uint4*>(&VaT[vb + (size_t)srow * S_ + sko]);
    if (tid < 128)
      vreg1 = *reinterpret_cast<const uint4*>(&VaT[vb + (size_t)(srow + 32) * S_ + sko]);
  };
  auto commit = [&](int buf) {
    short* Kd = (short*)(smem + buf * 9216);
    short* Vd = (short*)(smem + 18432 + buf * 6912);
    *reinterpret_cast<uint4*>(&Kd[srow * KPAD + sko]) = kreg0;
    *reinterpret_cast<uint4*>(&Kd[(srow + 32) * KPAD + sko]) = kreg1;
    *reinterpret_cast<uint4*>(&Vd[srow * KPAD + sko]) = vreg0;
    if (tid < 128)
      *reinterpret_cast<uint4*>(&Vd[(srow + 32) * KPAD + sko]) = vreg1;
  };

  issue(jt0);
  commit(0);
  __syncthreads();

  for (int j = 0; j < NJ; j++) {
    int cur = j & 1;
    if (j + 1 < NJ) issue(jt0 + j + 1);
    const short* Kc = (const short*)(smem + cur * 9216);
    const short* Vc = (const short*)(smem + 18432 + cur * 6912);
    short8 pA[2], pB[2];
#pragma unroll
    for (int sub = 0; sub < 4; sub++) {
      short8 ka0 = *reinterpret_cast<const short8*>(&Kc[(sub * 16 + t) * KPAD + kf]);
      short8 ka1 = *reinterpret_cast<const short8*>(&Kc[(sub * 16 + t) * KPAD + 32 + kf]);
      f32x4 sA = {}, sB = {};
      sA = __builtin_amdgcn_mfma_f32_16x16x32_bf16(ka0, aq[0][0], sA, 0, 0, 0);
      sA = __builtin_amdgcn_mfma_f32_16x16x32_bf16(ka1, aq[0][1], sA, 0, 0, 0);
      sB = __builtin_amdgcn_mfma_f32_16x16x32_bf16(ka0, aq[1][0], sB, 0, 0, 0);
      sB = __builtin_amdgcn_mfma_f32_16x16x32_bf16(ka1, aq[1][1], sB, 0, 0, 0);
      float a0 = exp2f(sA[0]), a1 = exp2f(sA[1]), a2 = exp2f(sA[2]), a3 = exp2f(sA[3]);
      float b0 = exp2f(sB[0]), b1 = exp2f(sB[1]), b2 = exp2f(sB[2]), b3 = exp2f(sB[3]);
      lsum0 += (a0 + a1) + (a2 + a3);
      lsum1 += (b0 + b1) + (b2 + b3);
      int ww = sub & 1, off = (sub >> 1) * 4;
      pA[ww][off + 0] = bf16_of(a0); pA[ww][off + 1] = bf16_of(a1);
      pA[ww][off + 2] = bf16_of(a2); pA[ww][off + 3] = bf16_of(a3);
      pB[ww][off + 0] = bf16_of(b0); pB[ww][off + 1] = bf16_of(b1);
      pB[ww][off + 2] = bf16_of(b2); pB[ww][off + 3] = bf16_of(b3);
    }
    // prefetch commit BEFORE PV: LDS writes to buf cur^1 overlap the MFMA cluster
    if (j + 1 < NJ) commit(cur ^ 1);
    __builtin_amdgcn_s_setprio(1);
#pragma unroll
    for (int tt = 0; tt < 3; tt++) {
#pragma unroll
      for (int w2 = 0; w2 < 2; w2++) {
        short8 va = *reinterpret_cast<const short8*>(&Vc[(tt * 16 + t) * KPAD + w2 * 32 + kf]);
        OaccA[tt] = __builtin_amdgcn_mfma_f32_16x16x32_bf16(va, pA[w2], OaccA[tt], 0, 0, 0);
        OaccB[tt] = __builtin_amdgcn_mfma_f32_16x16x32_bf16(va, pB[w2], OaccB[tt], 0, 0, 0);
      }
    }
    __builtin_amdgcn_s_setprio(0);
    __syncthreads();
  }

  lsum0 += __shfl_xor(lsum0, 16); lsum0 += __shfl_xor(lsum0, 32);
  lsum1 += __shfl_xor(lsum1, 16); lsum1 += __shfl_xor(lsum1, 32);

  float* Of = (float*)smem;
#pragma unroll
  for (int tt = 0; tt < 3; tt++)
#pragma unroll
    for (int r = 0; r < 4; r++) {
      Of[(w * 32 + t) * 52 + tt * 16 + g * 4 + r] = OaccA[tt][r];
      Of[(w * 32 + 16 + t) * 52 + tt * 16 + g * 4 + r] = OaccB[tt][r];
    }
  if (lane < 16) {
    size_t lb = (size_t)(split * NBH + bhv) * S_ + q0w + lane;
    AccL[lb] = lsum0;
    AccL[lb + 16] = lsum1;
  }
  __syncthreads();
  short* CtxP = Ctx + (size_t)split * NBH * S_ * 48;
  size_t obase = bh + it * 128;
  for (int task = tid; task < 768; task += 256) {
    int row = task / 6, c8 = task % 6;
    const float* src = &Of[row * 52 + c8 * 8];
    short8 o;
#pragma unroll
    for (int i = 0; i < 8; i++) o[i] = bf16_of(src[i]);
    *reinterpret_cast<short8*>(&CtxP[(obase + row) * 48 + c8 * 8]) = o;
  }
}

// ---------------- output projection + fused 4-way split-merge + fused point_proj ----------------

__global__ __launch_bounds__(512) void out_gemm(
    const short* __restrict__ Ctx, const float* __restrict__ AccL,
    const short* __restrict__ Wot, const float* __restrict__ bo,
    const float* __restrict__ Wpo, const float* __restrict__ bpo,
    float* __restrict__ Out) {
  const size_t CTXSZ = (size_t)NBH * S_ * 48;
  int m0 = blockIdx.x * 64;
  int tid = threadIdx.x;
  int b = m0 >> 11, sbase = m0 & 2047;

  if (blockIdx.y == 4) {
    int row = tid >> 3, hh = tid & 7;
    int m = m0 + row, s = sbase + row;
    size_t rowO = (size_t)(b * 8 + hh) * S_ + s;
    float l = 0.f;
#pragma unroll
    for (int sp = 0; sp < NSPLIT; sp++) l += AccL[(size_t)sp * NBH * S_ + rowO];
    float inv = 1.0f / l;
    float a0 = 0.f, a1 = 0.f, a2 = 0.f;
#pragma unroll
    for (int half = 0; half < 2; half++) {
      float sum[8] = {};
#pragma unroll
      for (int sp = 0; sp < NSPLIT; sp++) {
        short8 v = *reinterpret_cast<const short8*>(&Ctx[sp * CTXSZ + rowO * 48 + 32 + half * 8]);
#pragma unroll
        for (int c = 0; c < 8; c++) sum[c] += f_of_bf16(v[c]);
      }
#pragma unroll
      for (int c = 0; c < 8; c++) {
        float val = sum[c] * inv;
        int j = hh * 16 + half * 8 + c;
        a0 += val * Wpo[j * 3 + 0];
        a1 += val * Wpo[j * 3 + 1];
        a2 += val * Wpo[j * 3 + 2];
      }
    }
    a0 += __shfl_xor(a0, 1); a0 += __shfl_xor(a0, 2); a0 += __shfl_xor(a0, 4);
    a1 += __shfl_xor(a1, 1); a1 += __shfl_xor(a1, 2); a1 += __shfl_xor(a1, 4);
    a2 += __shfl_xor(a2, 1); a2 += __shfl_xor(a2, 2); a2 += __shfl_xor(a2, 4);
    if (hh == 0) {
      float* po = Out + (size_t)MTOT * 256;
      po[(size_t)m * 3 + 0] = a0 + bpo[0];
      po[(size_t)m * 3 + 1] = a1 + bpo[1];
      po[(size_t)m * 3 + 2] = a2 + bpo[2];
    }
    return;
  }

  __shared__ __align__(16) short As[64 * 136];
  __shared__ __align__(16) short Bs[64 * 136];
  int n0 = blockIdx.y * 64;
  int lane = tid & 63, w = tid >> 6;
  int t = lane & 15, g = lane >> 4, kf = g * 8;
  int wm = w & 3, wn = w >> 2;
  f32x4 acc[2] = {};
  int srow = tid >> 3, skc = (tid & 7) * 16;
  for (int ph = 0; ph < 2; ph++) {
    int k0 = ph * 128;
    __syncthreads();
    {
      int kg = k0 + skc;
      int hh = kg >> 5, d0 = kg & 31;
      size_t rowO = (size_t)(b * 8 + hh) * S_ + sbase + srow;
      float l = 0.f;
#pragma unroll
      for (int sp = 0; sp < NSPLIT; sp++) l += AccL[(size_t)sp * NBH * S_ + rowO];
      float inv = 1.0f / l;
#pragma unroll
      for (int half = 0; half < 2; half++) {
        float sum[8] = {};
#pragma unroll
        for (int sp = 0; sp < NSPLIT; sp++) {
          short8 a = *reinterpret_cast<const short8*>(&Ctx[sp * CTXSZ + rowO * 48 + d0 + half * 8]);
#pragma unroll
          for (int c = 0; c < 8; c++) sum[c] += f_of_bf16(a[c]);
        }
        short8 o;
#pragma unroll
        for (int c = 0; c < 8; c++) o[c] = bf16_of(sum[c] * inv);
        *reinterpret_cast<short8*>(&As[srow * 136 + skc + half * 8]) = o;
      }
      *reinterpret_cast<uint4*>(&Bs[srow * 136 + skc]) =
          *reinterpret_cast<const uint4*>(&Wot[(size_t)(n0 + srow) * 256 + kg]);
      *reinterpret_cast<uint4*>(&Bs[srow * 136 + skc + 8]) =
          *reinterpret_cast<const uint4*>(&Wot[(size_t)(n0 + srow) * 256 + kg + 8]);
    }
    __syncthreads();
#pragma unroll
    for (int kk = 0; kk < 4; kk++) {
      short8 a = *reinterpret_cast<const short8*>(&As[(wm * 16 + t) * 136 + kk * 32 + kf]);
#pragma unroll
      for (int jj = 0; jj < 2; jj++) {
        short8 bb = *reinterpret_cast<const short8*>(&Bs[(wn * 32 + jj * 16 + t) * 136 + kk * 32 + kf]);
        acc[jj] = __builtin_amdgcn_mfma_f32_16x16x32_bf16(a, bb, acc[jj], 0, 0, 0);
      }
    }
  }
#pragma unroll
  for (int jj = 0; jj < 2; jj++)
#pragma unroll
    for (int r = 0; r < 4; r++) {
      int mrow = m0 + wm * 16 + g * 4 + r;
      int n = n0 + wn * 32 + jj * 16 + t;
      Out[(size_t)mrow * 256 + n] = acc[jj][r] + bo[n];
    }
}

// ---------------- launch ----------------

extern "C" void kernel_launch(void* const* d_in, const int* in_sizes, int n_in,
                              void* d_out, int out_size, void* d_ws, size_t ws_size,
                              hipStream_t stream) {
  const float* seq    = (const float*)d_in[0];
  const float* coords = (const float*)d_in[1];
  const int*   mask   = (const int*)d_in[3];
  const float* Wq  = (const float*)d_in[4];
  const float* bq  = (const float*)d_in[5];
  const float* Wk  = (const float*)d_in[6];
  const float* bk  = (const float*)d_in[7];
  const float* Wv  = (const float*)d_in[8];
  const float* bv  = (const float*)d_in[9];
  const float* Wpq = (const float*)d_in[10];
  const float* bpq = (const float*)d_in[11];
  const float* Wpk = (const float*)d_in[12];
  const float* bpk = (const float*)d_in[13];
  const float* Wo  = (const float*)d_in[14];
  const float* bo  = (const float*)d_in[15];
  const float* Wpo = (const float*)d_in[16];
  const float* bpo = (const float*)d_in[17];
  float* out = (float*)d_out;

  char* ws = (char*)d_ws;
  short* Wqkv_t = (short*)ws; ws += 768 * 256 * 2;
  short* Wo_t   = (short*)ws; ws += 256 * 256 * 2;
  short* Xb     = (short*)ws; ws += (size_t)MTOT * D_ * 2;
  short* Qa     = (short*)ws; ws += (size_t)NBH * S_ * AUGQ * 2;
  short* Ka     = (short*)ws; ws += (size_t)NBH * S_ * AUGQ * 2;
  short* VaT    = (short*)ws; ws += (size_t)NBH * 48 * S_ * 2;
  short* Ctx    = (short*)ws; ws += (size_t)NSPLIT * NBH * S_ * 48 * 2;
  float* AccL   = (float*)ws; ws += (size_t)NSPLIT * NBH * S_ * 4;

  prep_all<<<960, 256, 0, stream>>>(Wq, Wk, Wv, Wo, seq, coords, mask,
                                    Wpq, bpq, Wpk, bpk,
                                    Wqkv_t, Wo_t, Xb, Qa, Ka, VaT);
  qkv_gemm<<<dim3(64, 12), 256, 0, stream>>>(Xb, Wqkv_t, bq, bk, bv, Qa, Ka, VaT);
  attn<<<1024, 256, 0, stream>>>(Qa, Ka, VaT, Ctx, AccL);
  out_gemm<<<dim3(64, 5), 512, 0, stream>>>(Ctx, AccL, Wo_t, bo, Wpo, bpo, out);
}

// Round 15
// 60.051 us; speedup vs baseline: 1.4697x; 1.0099x over previous
//
#include <hip/hip_runtime.h>
#include <hip/hip_bf16.h>

#define D_ 256
#define H_ 8
#define B_ 2
#define S_ 2048
#define MTOT 4096
#define AUGQ 64          // q(32) + pq(16) + [maskbias](1) + pad(15)
#define NBH 16           // B_*H_
#define KPAD 72
#define NSPLIT 4
#define NJ 8             // key tiles (of 64) per split
#define LOG2E 1.4426950408889634f

typedef __attribute__((ext_vector_type(8))) short short8;
typedef __attribute__((ext_vector_type(4))) short short4v;
typedef __attribute__((ext_vector_type(4))) float f32x4;

static __device__ __forceinline__ short bf16_of(float f) {
  union { __hip_bfloat16 h; short s; } u;
  u.h = __float2bfloat16(f);
  return u.s;
}
static __device__ __forceinline__ float f_of_bf16(short s) {
  union { float f; unsigned int u; } u;
  u.u = ((unsigned int)(unsigned short)s) << 16;
  return u.f;
}

// key permutation within a 64-key tile: V column c holds key sinv(c)
static __device__ __forceinline__ int sinv64(int c) {
  return (((((c >> 2) & 1) << 1) | ((c >> 5) & 1)) << 4) + (((c >> 3) & 3) << 2) + (c & 3);
}

// ---------------- prep: sectioned by blockIdx ----------------

__global__ __launch_bounds__(256) void prep_all(
    const float* __restrict__ Wq, const float* __restrict__ Wk,
    const float* __restrict__ Wv, const float* __restrict__ Wo,
    const float* __restrict__ X, const float* __restrict__ coords,
    const int* __restrict__ mask,
    const float* __restrict__ Wpq, const float* __restrict__ bpq,
    const float* __restrict__ Wpk, const float* __restrict__ bpk,
    short* __restrict__ Wqkv_t, short* __restrict__ Wo_t,
    short* __restrict__ Xb,
    short* __restrict__ Qa, short* __restrict__ Ka, short* __restrict__ VaT) {
  int bid = blockIdx.x, tid = threadIdx.x;

  if (bid < 64) {
    __shared__ short T[64][72];
    const float* src;
    short* dst;
    int k0, n0g;
    if (bid < 48) {
      int nt = bid >> 2;
      k0 = (bid & 3) * 64;
      n0g = nt * 64;
      src = (n0g < 256) ? Wq : (n0g < 512 ? Wk : Wv);
      dst = Wqkv_t;
    } else {
      int t2 = bid - 48;
      k0 = (t2 & 3) * 64;
      n0g = (t2 >> 2) * 64;
      src = Wo;
      dst = Wo_t;
    }
    int ncol = n0g & 255;
    int rr = tid >> 4, cc = (tid & 15) * 4;
#pragma unroll
    for (int i = 0; i < 4; i++) {
      int r = rr + i * 16;
      f32x4 v = *reinterpret_cast<const f32x4*>(&src[(size_t)(k0 + r) * 256 + ncol + cc]);
      T[cc + 0][r] = bf16_of(v[0]);
      T[cc + 1][r] = bf16_of(v[1]);
      T[cc + 2][r] = bf16_of(v[2]);
      T[cc + 3][r] = bf16_of(v[3]);
    }
    __syncthreads();
    int n = tid >> 2, kk = (tid & 3) * 16;
    *reinterpret_cast<short8*>(&dst[(size_t)(n0g + n) * 256 + k0 + kk]) =
        *reinterpret_cast<const short8*>(&T[n][kk]);
    *reinterpret_cast<short8*>(&dst[(size_t)(n0g + n) * 256 + k0 + kk + 8]) =
        *reinterpret_cast<const short8*>(&T[n][kk + 8]);
    return;
  }

  if (bid < 576) {
    size_t i = (size_t)(bid - 64) * 2048 + tid * 8;
    f32x4 v0 = *reinterpret_cast<const f32x4*>(&X[i]);
    f32x4 v1 = *reinterpret_cast<const f32x4*>(&X[i + 4]);
    short8 o;
    o[0] = bf16_of(v0[0]); o[1] = bf16_of(v0[1]); o[2] = bf16_of(v0[2]); o[3] = bf16_of(v0[3]);
    o[4] = bf16_of(v1[0]); o[5] = bf16_of(v1[1]); o[6] = bf16_of(v1[2]); o[7] = bf16_of(v1[3]);
    *reinterpret_cast<short8*>(&Xb[i]) = o;
    return;
  }

  if (bid < 704) {
    int idx = (bid - 576) * 256 + tid;
    int m = idx >> 3, h = idx & 7;
    int b = m >> 11, s = m & 2047;
    float r0 = coords[m * 9 + 3], r1 = coords[m * 9 + 4], r2 = coords[m * 9 + 5];
    size_t base = ((size_t)(b * 8 + h) * S_ + s) * AUGQ;
    short8 pqv[2], pkv[2];
#pragma unroll
    for (int c = 0; c < 2; c++)
#pragma unroll
      for (int i = 0; i < 8; i++) {
        int j = h * 16 + c * 8 + i;
        float pq = r0 * Wpq[j] + r1 * Wpq[128 + j] + r2 * Wpq[256 + j] + bpq[j];
        float pk = r0 * Wpk[j] + r1 * Wpk[128 + j] + r2 * Wpk[256 + j] + bpk[j];
        pqv[c][i] = bf16_of(pq * LOG2E);
        pkv[c][i] = bf16_of(pk * 0.25f);
      }
    short8 padq = {};
    padq[0] = bf16_of(LOG2E);
    short8 padk = {};
    padk[0] = mask[m] ? (short)0 : bf16_of(-1e9f);
    short8 z = {};
    *reinterpret_cast<short8*>(&Qa[base + 32]) = pqv[0];
    *reinterpret_cast<short8*>(&Qa[base + 40]) = pqv[1];
    *reinterpret_cast<short8*>(&Qa[base + 48]) = padq;
    *reinterpret_cast<short8*>(&Qa[base + 56]) = z;
    *reinterpret_cast<short8*>(&Ka[base + 32]) = pkv[0];
    *reinterpret_cast<short8*>(&Ka[base + 40]) = pkv[1];
    *reinterpret_cast<short8*>(&Ka[base + 48]) = padk;
    *reinterpret_cast<short8*>(&Ka[base + 56]) = z;
    return;
  }

  {
    int idx = (bid - 704) * 256 + tid;
    int s8 = idx & 255, p = (idx >> 8) & 15, bh = idx >> 12;
    int b = bh >> 3, h = bh & 7, j = h * 16 + p;
    float w0 = Wpq[j], w1 = Wpq[128 + j], w2 = Wpq[256 + j], bb = bpq[j];
    short8 o;
#pragma unroll
    for (int i = 0; i < 8; i++) {
      int c = (s8 & 7) * 8 + i;
      int m = b * 2048 + (s8 >> 3) * 64 + sinv64(c);
      o[i] = bf16_of(coords[m * 9 + 3] * w0 + coords[m * 9 + 4] * w1 +
                     coords[m * 9 + 5] * w2 + bb);
    }
    *reinterpret_cast<short8*>(&VaT[((size_t)bh * 48 + 32 + p) * S_ + s8 * 8]) = o;
  }
}

// ---------------- QKV GEMM (M=4096, N=768, K=256), 64x64 tile (768 blocks, 3/CU) ----------------

__global__ __launch_bounds__(256) void qkv_gemm(
    const short* __restrict__ Xb, const short* __restrict__ Wt,
    const float* __restrict__ bq, const float* __restrict__ bk, const float* __restrict__ bv,
    short* __restrict__ Qa, short* __restrict__ Ka, short* __restrict__ VaT) {
  __shared__ __align__(16) short As[64 * 136];
  __shared__ __align__(16) short Bs[64 * 136];
  int m0 = blockIdx.x * 64, n0 = blockIdx.y * 64;
  int tid = threadIdx.x, lane = tid & 63, w = tid >> 6;
  int t = lane & 15, g = lane >> 4, kf = g * 8;
  int wr = (w >> 1) * 32, wc = (w & 1) * 32;
  f32x4 acc[2][2] = {};
  int srow = tid >> 2, skc = (tid & 3) * 32;
  for (int ph = 0; ph < 2; ph++) {
    int k0 = ph * 128;
    __syncthreads();
    {
      const uint4* xsrc = reinterpret_cast<const uint4*>(&Xb[(size_t)(m0 + srow) * 256 + k0 + skc]);
      const uint4* wsrc = reinterpret_cast<const uint4*>(&Wt[(size_t)(n0 + srow) * 256 + k0 + skc]);
#pragma unroll
      for (int i = 0; i < 4; i++)
        *reinterpret_cast<uint4*>(&As[srow * 136 + skc + i * 8]) = xsrc[i];
#pragma unroll
      for (int i = 0; i < 4; i++)
        *reinterpret_cast<uint4*>(&Bs[srow * 136 + skc + i * 8]) = wsrc[i];
    }
    __syncthreads();
#pragma unroll
    for (int kk = 0; kk < 4; kk++) {
      short8 a[2], bb[2];
#pragma unroll
      for (int i = 0; i < 2; i++)
        a[i] = *reinterpret_cast<const short8*>(&As[(wr + i * 16 + t) * 136 + kk * 32 + kf]);
#pragma unroll
      for (int jj = 0; jj < 2; jj++)
        bb[jj] = *reinterpret_cast<const short8*>(&Bs[(wc + jj * 16 + t) * 136 + kk * 32 + kf]);
#pragma unroll
      for (int i = 0; i < 2; i++)
#pragma unroll
        for (int jj = 0; jj < 2; jj++)
          acc[i][jj] = __builtin_amdgcn_mfma_f32_16x16x32_bf16(a[i], bb[jj], acc[i][jj], 0, 0, 0);
    }
  }
  __syncthreads();
  short* Cs = As;
  const float scale = 0.17677669529663687f * LOG2E;  // (1/sqrt(32)) * log2e
  int b = m0 >> 11, sbase = m0 & 2047;
#pragma unroll
  for (int i = 0; i < 2; i++)
#pragma unroll
    for (int jj = 0; jj < 2; jj++)
#pragma unroll
      for (int r = 0; r < 4; r++) {
        int rl = wr + i * 16 + g * 4 + r;
        int cl = wc + jj * 16 + t;
        int n = n0 + cl;
        float v = acc[i][jj][r];
        if (n < 256) v = (v + bq[n]) * scale;
        else if (n < 512) v = v + bk[n - 256];
        else v = v + bv[n - 512];
        Cs[rl * 72 + cl] = bf16_of(v);
      }
  __syncthreads();
  if (n0 < 512) {
#pragma unroll
    for (int i2 = 0; i2 < 2; i2++) {
      int task = tid + i2 * 256;
      int row = task >> 3, c = task & 7;
      int n = n0 + c * 8;
      short* dst = (n < 256) ? Qa : Ka;
      int nn = n & 255;
      int hh = nn >> 5, d = nn & 31;
      *reinterpret_cast<short8*>(&dst[((size_t)(b * 8 + hh) * S_ + sbase + row) * AUGQ + d]) =
          *reinterpret_cast<const short8*>(&Cs[row * 72 + c * 8]);
    }
  } else {
    int hv0 = (n0 - 512) >> 5;
#pragma unroll
    for (int i2 = 0; i2 < 2; i2++) {
      int task = tid + i2 * 256;
      int fl = task >> 3, s8 = task & 7;
      short8 o;
#pragma unroll
      for (int i = 0; i < 8; i++) o[i] = Cs[sinv64(s8 * 8 + i) * 72 + fl];
      int hh = hv0 + (fl >> 5), d = fl & 31;
      *reinterpret_cast<short8*>(&VaT[((size_t)(b * 8 + hh) * 48 + d) * S_ + sbase + s8 * 8]) = o;
    }
  }
}

// ---------------- flash attention: swapped QK^T, register P, K=32 PV ----------------
// grid 1024 (XCD-swizzled, 4 blocks/CU); block 256 = 4 waves, each wave 32 queries.
// lsum computed on the MFMA pipe via constant all-ones A-fragment (feature row 48):
// D[0][q] = sum_k P[k][q]; lanes g=0 hold it in Oacc3[0] at col=q=t.

__global__ __launch_bounds__(256, 4) void attn(
    const short* __restrict__ Qa, const short* __restrict__ Ka,
    const short* __restrict__ VaT,
    short* __restrict__ Ctx, float* __restrict__ AccL) {
  __shared__ __align__(16) char smem[32256];

  int bid = blockIdx.x;
  int xcd = bid & 7, slot = bid >> 3;
  int gidx = xcd * 8 + (slot >> 4);
  int it = slot & 15;
  int split = gidx & 3;
  int bhv = gidx >> 2;

  int tid = threadIdx.x, lane = tid & 63, w = tid >> 6;
  int t = lane & 15, g = lane >> 4, kf = g * 8;
  int q0w = it * 128 + w * 32;
  size_t bh = (size_t)bhv * S_;

  short8 aq[2][2];
#pragma unroll
  for (int g2 = 0; g2 < 2; g2++)
#pragma unroll
    for (int c = 0; c < 2; c++)
      aq[g2][c] = *reinterpret_cast<const short8*>(
          &Qa[(bh + q0w + g2 * 16 + t) * AUGQ + c * 32 + kf]);

  // ones A-fragment: row 0 (of the virtual lsum tile) = 1.0, rows 1-15 = 0
  short8 onesA = {};
  if (t == 0) {
#pragma unroll
    for (int i = 0; i < 8; i++) onesA[i] = 0x3F80;  // bf16(1.0)
  }

  f32x4 OaccA[3] = {}, OaccB[3] = {};
  f32x4 OaccA3 = {}, OaccB3 = {};

  uint4 kreg0, kreg1, vreg0, vreg1;
  int srow = tid >> 3, sko = (tid & 7) * 8;
  const int jt0 = split * NJ;

  auto issue = [&](int jt) {
    const uint4* ks = reinterpret_cast<const uint4*>(&Ka[(bh + jt * 64) * AUGQ]);
    kreg0 = ks[tid];
    kreg1 = ks[tid + 256];
    size_t vb = (size_t)bhv * 48 * S_ + jt * 64;
    vreg0 = *reinterpret_cast<const uint4*>(&VaT[vb + (size_t)srow * S_ + sko]);
    if (tid < 128)
      vreg1 = *reinterpret_cast<const uint4*>(&VaT[vb + (size_t)(srow + 32) * S_ + sko]);
  };
  auto commit = [&](int buf) {
    short* Kd = (short*)(smem + buf * 9216);
    short* Vd = (short*)(smem + 18432 + buf * 6912);
    *reinterpret_cast<uint4*>(&Kd[srow * KPAD + sko]) = kreg0;
    *reinterpret_cast<uint4*>(&Kd[(srow + 32) * KPAD + sko]) = kreg1;
    *reinterpret_cast<uint4*>(&Vd[srow * KPAD + sko]) = vreg0;
    if (tid < 128)
      *reinterpret_cast<uint4*>(&Vd[(srow + 32) * KPAD + sko]) = vreg1;
  };

  issue(jt0);
  commit(0);
  __syncthreads();

  for (int j = 0; j < NJ; j++) {
    int cur = j & 1;
    if (j + 1 < NJ) issue(jt0 + j + 1);
    const short* Kc = (const short*)(smem + cur * 9216);
    const short* Vc = (const short*)(smem + 18432 + cur * 6912);
    short8 pA[2], pB[2];
#pragma unroll
    for (int sub = 0; sub < 4; sub++) {
      short8 ka0 = *reinterpret_cast<const short8*>(&Kc[(sub * 16 + t) * KPAD + kf]);
      short8 ka1 = *reinterpret_cast<const short8*>(&Kc[(sub * 16 + t) * KPAD + 32 + kf]);
      f32x4 sA = {}, sB = {};
      sA = __builtin_amdgcn_mfma_f32_16x16x32_bf16(ka0, aq[0][0], sA, 0, 0, 0);
      sA = __builtin_amdgcn_mfma_f32_16x16x32_bf16(ka1, aq[0][1], sA, 0, 0, 0);
      sB = __builtin_amdgcn_mfma_f32_16x16x32_bf16(ka0, aq[1][0], sB, 0, 0, 0);
      sB = __builtin_amdgcn_mfma_f32_16x16x32_bf16(ka1, aq[1][1], sB, 0, 0, 0);
      float a0 = exp2f(sA[0]), a1 = exp2f(sA[1]), a2 = exp2f(sA[2]), a3 = exp2f(sA[3]);
      float b0 = exp2f(sB[0]), b1 = exp2f(sB[1]), b2 = exp2f(sB[2]), b3 = exp2f(sB[3]);
      int ww = sub & 1, off = (sub >> 1) * 4;
      pA[ww][off + 0] = bf16_of(a0); pA[ww][off + 1] = bf16_of(a1);
      pA[ww][off + 2] = bf16_of(a2); pA[ww][off + 3] = bf16_of(a3);
      pB[ww][off + 0] = bf16_of(b0); pB[ww][off + 1] = bf16_of(b1);
      pB[ww][off + 2] = bf16_of(b2); pB[ww][off + 3] = bf16_of(b3);
    }
    // prefetch commit BEFORE PV: LDS writes to buf cur^1 overlap the MFMA cluster
    if (j + 1 < NJ) commit(cur ^ 1);
    __builtin_amdgcn_s_setprio(1);
#pragma unroll
    for (int tt = 0; tt < 3; tt++) {
#pragma unroll
      for (int w2 = 0; w2 < 2; w2++) {
        short8 va = *reinterpret_cast<const short8*>(&Vc[(tt * 16 + t) * KPAD + w2 * 32 + kf]);
        OaccA[tt] = __builtin_amdgcn_mfma_f32_16x16x32_bf16(va, pA[w2], OaccA[tt], 0, 0, 0);
        OaccB[tt] = __builtin_amdgcn_mfma_f32_16x16x32_bf16(va, pB[w2], OaccB[tt], 0, 0, 0);
      }
    }
    // lsum tile: D[0][q] += sum_k P[k][q] on the matrix pipe
#pragma unroll
    for (int w2 = 0; w2 < 2; w2++) {
      OaccA3 = __builtin_amdgcn_mfma_f32_16x16x32_bf16(onesA, pA[w2], OaccA3, 0, 0, 0);
      OaccB3 = __builtin_amdgcn_mfma_f32_16x16x32_bf16(onesA, pB[w2], OaccB3, 0, 0, 0);
    }
    __builtin_amdgcn_s_setprio(0);
    __syncthreads();
  }

  float* Of = (float*)smem;
#pragma unroll
  for (int tt = 0; tt < 3; tt++)
#pragma unroll
    for (int r = 0; r < 4; r++) {
      Of[(w * 32 + t) * 52 + tt * 16 + g * 4 + r] = OaccA[tt][r];
      Of[(w * 32 + 16 + t) * 52 + tt * 16 + g * 4 + r] = OaccB[tt][r];
    }
  if (lane < 16) {
    size_t lb = (size_t)(split * NBH + bhv) * S_ + q0w + lane;
    AccL[lb] = OaccA3[0];
    AccL[lb + 16] = OaccB3[0];
  }
  __syncthreads();
  short* CtxP = Ctx + (size_t)split * NBH * S_ * 48;
  size_t obase = bh + it * 128;
  for (int task = tid; task < 768; task += 256) {
    int row = task / 6, c8 = task % 6;
    const float* src = &Of[row * 52 + c8 * 8];
    short8 o;
#pragma unroll
    for (int i = 0; i < 8; i++) o[i] = bf16_of(src[i]);
    *reinterpret_cast<short8*>(&CtxP[(obase + row) * 48 + c8 * 8]) = o;
  }
}

// ---------------- output projection + fused 4-way split-merge + fused point_proj ----------------

__global__ __launch_bounds__(512) void out_gemm(
    const short* __restrict__ Ctx, const float* __restrict__ AccL,
    const short* __restrict__ Wot, const float* __restrict__ bo,
    const float* __restrict__ Wpo, const float* __restrict__ bpo,
    float* __restrict__ Out) {
  const size_t CTXSZ = (size_t)NBH * S_ * 48;
  int m0 = blockIdx.x * 64;
  int tid = threadIdx.x;
  int b = m0 >> 11, sbase = m0 & 2047;

  if (blockIdx.y == 4) {
    int row = tid >> 3, hh = tid & 7;
    int m = m0 + row, s = sbase + row;
    size_t rowO = (size_t)(b * 8 + hh) * S_ + s;
    float l = 0.f;
#pragma unroll
    for (int sp = 0; sp < NSPLIT; sp++) l += AccL[(size_t)sp * NBH * S_ + rowO];
    float inv = 1.0f / l;
    float a0 = 0.f, a1 = 0.f, a2 = 0.f;
#pragma unroll
    for (int half = 0; half < 2; half++) {
      float sum[8] = {};
#pragma unroll
      for (int sp = 0; sp < NSPLIT; sp++) {
        short8 v = *reinterpret_cast<const short8*>(&Ctx[sp * CTXSZ + rowO * 48 + 32 + half * 8]);
#pragma unroll
        for (int c = 0; c < 8; c++) sum[c] += f_of_bf16(v[c]);
      }
#pragma unroll
      for (int c = 0; c < 8; c++) {
        float val = sum[c] * inv;
        int j = hh * 16 + half * 8 + c;
        a0 += val * Wpo[j * 3 + 0];
        a1 += val * Wpo[j * 3 + 1];
        a2 += val * Wpo[j * 3 + 2];
      }
    }
    a0 += __shfl_xor(a0, 1); a0 += __shfl_xor(a0, 2); a0 += __shfl_xor(a0, 4);
    a1 += __shfl_xor(a1, 1); a1 += __shfl_xor(a1, 2); a1 += __shfl_xor(a1, 4);
    a2 += __shfl_xor(a2, 1); a2 += __shfl_xor(a2, 2); a2 += __shfl_xor(a2, 4);
    if (hh == 0) {
      float* po = Out + (size_t)MTOT * 256;
      po[(size_t)m * 3 + 0] = a0 + bpo[0];
      po[(size_t)m * 3 + 1] = a1 + bpo[1];
      po[(size_t)m * 3 + 2] = a2 + bpo[2];
    }
    return;
  }

  __shared__ __align__(16) short As[64 * 136];
  __shared__ __align__(16) short Bs[64 * 136];
  int n0 = blockIdx.y * 64;
  int lane = tid & 63, w = tid >> 6;
  int t = lane & 15, g = lane >> 4, kf = g * 8;
  int wm = w & 3, wn = w >> 2;
  f32x4 acc[2] = {};
  int srow = tid >> 3, skc = (tid & 7) * 16;
  for (int ph = 0; ph < 2; ph++) {
    int k0 = ph * 128;
    __syncthreads();
    {
      int kg = k0 + skc;
      int hh = kg >> 5, d0 = kg & 31;
      size_t rowO = (size_t)(b * 8 + hh) * S_ + sbase + srow;
      float l = 0.f;
#pragma unroll
      for (int sp = 0; sp < NSPLIT; sp++) l += AccL[(size_t)sp * NBH * S_ + rowO];
      float inv = 1.0f / l;
#pragma unroll
      for (int half = 0; half < 2; half++) {
        float sum[8] = {};
#pragma unroll
        for (int sp = 0; sp < NSPLIT; sp++) {
          short8 a = *reinterpret_cast<const short8*>(&Ctx[sp * CTXSZ + rowO * 48 + d0 + half * 8]);
#pragma unroll
          for (int c = 0; c < 8; c++) sum[c] += f_of_bf16(a[c]);
        }
        short8 o;
#pragma unroll
        for (int c = 0; c < 8; c++) o[c] = bf16_of(sum[c] * inv);
        *reinterpret_cast<short8*>(&As[srow * 136 + skc + half * 8]) = o;
      }
      *reinterpret_cast<uint4*>(&Bs[srow * 136 + skc]) =
          *reinterpret_cast<const uint4*>(&Wot[(size_t)(n0 + srow) * 256 + kg]);
      *reinterpret_cast<uint4*>(&Bs[srow * 136 + skc + 8]) =
          *reinterpret_cast<const uint4*>(&Wot[(size_t)(n0 + srow) * 256 + kg + 8]);
    }
    __syncthreads();
#pragma unroll
    for (int kk = 0; kk < 4; kk++) {
      short8 a = *reinterpret_cast<const short8*>(&As[(wm * 16 + t) * 136 + kk * 32 + kf]);
#pragma unroll
      for (int jj = 0; jj < 2; jj++) {
        short8 bb = *reinterpret_cast<const short8*>(&Bs[(wn * 32 + jj * 16 + t) * 136 + kk * 32 + kf]);
        acc[jj] = __builtin_amdgcn_mfma_f32_16x16x32_bf16(a, bb, acc[jj], 0, 0, 0);
      }
    }
  }
#pragma unroll
  for (int jj = 0; jj < 2; jj++)
#pragma unroll
    for (int r = 0; r < 4; r++) {
      int mrow = m0 + wm * 16 + g * 4 + r;
      int n = n0 + wn * 32 + jj * 16 + t;
      Out[(size_t)mrow * 256 + n] = acc[jj][r] + bo[n];
    }
}

// ---------------- launch ----------------

extern "C" void kernel_launch(void* const* d_in, const int* in_sizes, int n_in,
                              void* d_out, int out_size, void* d_ws, size_t ws_size,
                              hipStream_t stream) {
  const float* seq    = (const float*)d_in[0];
  const float* coords = (const float*)d_in[1];
  const int*   mask   = (const int*)d_in[3];
  const float* Wq  = (const float*)d_in[4];
  const float* bq  = (const float*)d_in[5];
  const float* Wk  = (const float*)d_in[6];
  const float* bk  = (const float*)d_in[7];
  const float* Wv  = (const float*)d_in[8];
  const float* bv  = (const float*)d_in[9];
  const float* Wpq = (const float*)d_in[10];
  const float* bpq = (const float*)d_in[11];
  const float* Wpk = (const float*)d_in[12];
  const float* bpk = (const float*)d_in[13];
  const float* Wo  = (const float*)d_in[14];
  const float* bo  = (const float*)d_in[15];
  const float* Wpo = (const float*)d_in[16];
  const float* bpo = (const float*)d_in[17];
  float* out = (float*)d_out;

  char* ws = (char*)d_ws;
  short* Wqkv_t = (short*)ws; ws += 768 * 256 * 2;
  short* Wo_t   = (short*)ws; ws += 256 * 256 * 2;
  short* Xb     = (short*)ws; ws += (size_t)MTOT * D_ * 2;
  short* Qa     = (short*)ws; ws += (size_t)NBH * S_ * AUGQ * 2;
  short* Ka     = (short*)ws; ws += (size_t)NBH * S_ * AUGQ * 2;
  short* VaT    = (short*)ws; ws += (size_t)NBH * 48 * S_ * 2;
  short* Ctx    = (short*)ws; ws += (size_t)NSPLIT * NBH * S_ * 48 * 2;
  float* AccL   = (float*)ws; ws += (size_t)NSPLIT * NBH * S_ * 4;

  prep_all<<<960, 256, 0, stream>>>(Wq, Wk, Wv, Wo, seq, coords, mask,
                                    Wpq, bpq, Wpk, bpk,
                                    Wqkv_t, Wo_t, Xb, Qa, Ka, VaT);
  qkv_gemm<<<dim3(64, 12), 256, 0, stream>>>(Xb, Wqkv_t, bq, bk, bv, Qa, Ka, VaT);
  attn<<<1024, 256, 0, stream>>>(Qa, Ka, VaT, Ctx, AccL);
  out_gemm<<<dim3(64, 5), 512, 0, stream>>>(Ctx, AccL, Wo_t, bo, Wpo, bpo, out);
}